// Round 1
// baseline (868.590 us; speedup 1.0000x reference)
//
#include <hip/hip_runtime.h>
#include <math.h>

#define S_  100
#define D_  30
#define T_  40
#define FT_ 512
#define FP_ 3
#define H_  64
#define G3  192
#define G4  256
#define M_  (D_*T_)   // 1200

__device__ __forceinline__ float sigm(float x){ return 1.0f/(1.0f+__expf(-x)); }

// ---------------------------------------------------------------- K1: GX = Wall @ x + bWall + bUall
#define BM 64
#define BN 64
#define BK 32
#define LDA 68

__global__ __launch_bounds__(256) void k_text_gemm(
    const float* __restrict__ text, const float* __restrict__ Wall,
    const float* __restrict__ bW, const float* __restrict__ bU,
    float* __restrict__ GX)
{
  const int s  = blockIdx.z;
  const int m0 = blockIdx.x * BM;
  const int n0 = blockIdx.y * BN;
  const int tid = threadIdx.x;
  const int tx = tid & 15, ty = tid >> 4;
  const float* X = text + (size_t)s * (M_*FT_);
  const float* W = Wall + (size_t)s * (G4*FT_);
  __shared__ float As[BK][LDA];
  __shared__ float Bs[BK][LDA];
  float acc[4][4];
  #pragma unroll
  for (int i=0;i<4;++i)
    #pragma unroll
    for (int j=0;j<4;++j) acc[i][j]=0.f;

  const int lr = tid >> 3;        // 0..31
  const int lc = (tid & 7) * 4;   // 0,4,...,28

  for (int k0 = 0; k0 < FT_; k0 += BK) {
    #pragma unroll
    for (int p = 0; p < 2; ++p) {
      int r = lr + p*32;
      int m = m0 + r;
      float4 v = make_float4(0.f,0.f,0.f,0.f);
      if (m < M_) v = *reinterpret_cast<const float4*>(X + (size_t)m*FT_ + k0 + lc);
      As[lc+0][r]=v.x; As[lc+1][r]=v.y; As[lc+2][r]=v.z; As[lc+3][r]=v.w;
    }
    #pragma unroll
    for (int p = 0; p < 2; ++p) {
      int r = lr + p*32;
      float4 v = *reinterpret_cast<const float4*>(W + (size_t)(n0 + r)*FT_ + k0 + lc);
      Bs[lc+0][r]=v.x; Bs[lc+1][r]=v.y; Bs[lc+2][r]=v.z; Bs[lc+3][r]=v.w;
    }
    __syncthreads();
    #pragma unroll
    for (int kk = 0; kk < BK; ++kk) {
      float4 a = *reinterpret_cast<const float4*>(&As[kk][ty*4]);
      float4 b = *reinterpret_cast<const float4*>(&Bs[kk][tx*4]);
      float av[4] = {a.x,a.y,a.z,a.w};
      float bv[4] = {b.x,b.y,b.z,b.w};
      #pragma unroll
      for (int i=0;i<4;++i)
        #pragma unroll
        for (int j=0;j<4;++j)
          acc[i][j] = fmaf(av[i], bv[j], acc[i][j]);
    }
    __syncthreads();
  }
  #pragma unroll
  for (int i=0;i<4;++i) {
    int m = m0 + ty*4 + i;
    if (m < M_) {
      #pragma unroll
      for (int j=0;j<4;++j) {
        int n = n0 + tx*4 + j;
        GX[((size_t)s*M_ + m)*G4 + n] = acc[i][j] + bW[s*G4+n] + bU[s*G4+n];
      }
    }
  }
}

// ---------------------------------------------------------------- K2: TimeLSTM + day attention -> news
__global__ __launch_bounds__(256) void k_timelstm(
    const float* __restrict__ GX, const float* __restrict__ Uall,
    const float* __restrict__ Wd, const float* __restrict__ bd,
    const float* __restrict__ taW, const float* __restrict__ tab,
    const float* __restrict__ ts, float* __restrict__ news)
{
  const int blk = blockIdx.x;
  const int s = blk / D_;
  const int d = blk % D_;
  const int tid = threadIdx.x;
  const int row = tid & 63, q = tid >> 6;
  __shared__ float hs[H_], cs[H_], gs[G4], pt[4][H_];
  __shared__ float outs[T_][H_+1];
  __shared__ float vs[H_], as_[T_];

  float u[64];
  {
    const float* Up = Uall + ((size_t)s*G4 + tid)*H_;
    #pragma unroll
    for (int j=0;j<64;++j) u[j] = Up[j];
  }
  float wd[16];
  {
    const float* Wp = Wd + ((size_t)s*H_ + row)*H_ + q*16;
    #pragma unroll
    for (int j=0;j<16;++j) wd[j] = Wp[j];
  }
  const float bdr = bd[s*H_ + row];
  if (tid < H_) { hs[tid]=0.f; cs[tid]=0.f; }
  __syncthreads();

  const float* gxp = GX + ((size_t)s*M_ + d*T_)*G4;
  const float* tsp = ts + ((size_t)s*D_ + d)*T_;

  for (int t=0; t<T_; ++t) {
    float p = 0.f;
    #pragma unroll
    for (int j=0;j<16;++j) p = fmaf(wd[j], cs[q*16+j], p);
    pt[q][row] = p;

    float g = gxp[t*G4 + tid];
    const float4* h4 = reinterpret_cast<const float4*>(hs);
    #pragma unroll
    for (int j4=0;j4<16;++j4) {
      float4 hv = h4[j4];
      g = fmaf(u[j4*4+0], hv.x, g);
      g = fmaf(u[j4*4+1], hv.y, g);
      g = fmaf(u[j4*4+2], hv.z, g);
      g = fmaf(u[j4*4+3], hv.w, g);
    }
    gs[tid] = sigm(g);
    __syncthreads();
    if (tid < H_) {
      float cs1 = tanhf(pt[0][tid]+pt[1][tid]+pt[2][tid]+pt[3][tid] + bdr);
      float tv = tsp[t];
      float cadj = cs[tid] - cs1 + cs1*tv;
      float c2 = gs[tid]*cadj + gs[64+tid]*gs[192+tid];
      float h2 = gs[128+tid]*tanhf(c2);
      cs[tid] = c2; hs[tid] = h2; outs[t][tid] = h2;
    }
    __syncthreads();
  }

  // attention: v = taW@h_last + tab ; scores = outs@v ; softmax ; news = a@outs
  {
    const float* Wp = taW + ((size_t)s*H_ + row)*H_ + q*16;
    float p = 0.f;
    #pragma unroll
    for (int j=0;j<16;++j) p = fmaf(Wp[j], hs[q*16+j], p);
    pt[q][row] = p;
    __syncthreads();
    if (tid < H_) vs[tid] = pt[0][tid]+pt[1][tid]+pt[2][tid]+pt[3][tid] + tab[s*H_+tid];
    __syncthreads();
    if (tid < T_) {
      float sc = 0.f;
      for (int h=0;h<H_;++h) sc = fmaf(outs[tid][h], vs[h], sc);
      as_[tid] = sc;
    }
    __syncthreads();
    if (tid == 0) {
      float m = -1e30f;
      for (int t=0;t<T_;++t) m = fmaxf(m, as_[t]);
      float sum = 0.f;
      for (int t=0;t<T_;++t) { float e = __expf(as_[t]-m); as_[t]=e; sum += e; }
      float inv = 1.0f/sum;
      for (int t=0;t<T_;++t) as_[t] *= inv;
    }
    __syncthreads();
    if (tid < H_) {
      float acc = 0.f;
      for (int t=0;t<T_;++t) acc = fmaf(as_[t], outs[t][tid], acc);
      news[((size_t)s*D_ + d)*H_ + tid] = acc;
    }
  }
}

// ---------------------------------------------------------------- K3: price GRU + attention -> xvec
__global__ __launch_bounds__(256) void k_price_gru(
    const float* __restrict__ price, const float* __restrict__ Wih,
    const float* __restrict__ Whh, const float* __restrict__ bih,
    const float* __restrict__ bhh, const float* __restrict__ paW,
    const float* __restrict__ pab, float* __restrict__ xvec)
{
  const int s = blockIdx.x;
  const int tid = threadIdx.x;
  const int row = tid & 63, q = tid >> 6;
  __shared__ float hs[H_];
  __shared__ float outs[D_][H_+1];
  __shared__ float gsum[128], gxn[64], ghn[64];
  __shared__ float pt[4][H_], vs[H_], as_[D_];

  float wih[3]; float whh[64]; float bihr=0.f, bhhr=0.f;
  if (tid < G3) {
    const float* wp = Wih + ((size_t)s*G3 + tid)*FP_;
    wih[0]=wp[0]; wih[1]=wp[1]; wih[2]=wp[2];
    const float* hp = Whh + ((size_t)s*G3 + tid)*H_;
    #pragma unroll
    for (int j=0;j<64;++j) whh[j]=hp[j];
    bihr = bih[s*G3+tid]; bhhr = bhh[s*G3+tid];
  }
  if (tid < H_) hs[tid]=0.f;
  __syncthreads();

  for (int d=0; d<D_; ++d) {
    const float* pp = price + ((size_t)s*D_ + d)*FP_;
    float p0=pp[0], p1=pp[1], p2=pp[2];
    if (tid < G3) {
      float gx = bihr + wih[0]*p0 + wih[1]*p1 + wih[2]*p2;
      float gh = bhhr;
      const float4* h4 = reinterpret_cast<const float4*>(hs);
      #pragma unroll
      for (int j4=0;j4<16;++j4) {
        float4 hv=h4[j4];
        gh = fmaf(whh[j4*4+0],hv.x,gh);
        gh = fmaf(whh[j4*4+1],hv.y,gh);
        gh = fmaf(whh[j4*4+2],hv.z,gh);
        gh = fmaf(whh[j4*4+3],hv.w,gh);
      }
      if (tid < 128) gsum[tid] = gx + gh;
      else { gxn[tid-128] = gx; ghn[tid-128] = gh; }
    }
    __syncthreads();
    if (tid < H_) {
      float r = sigm(gsum[tid]);
      float z = sigm(gsum[64+tid]);
      float n = tanhf(gxn[tid] + r*ghn[tid]);
      float h2 = (1.f-z)*n + z*hs[tid];
      hs[tid]=h2; outs[d][tid]=h2;
    }
    __syncthreads();
  }

  {
    const float* Wp = paW + ((size_t)s*H_ + row)*H_ + q*16;
    float p = 0.f;
    #pragma unroll
    for (int j=0;j<16;++j) p = fmaf(Wp[j], hs[q*16+j], p);
    pt[q][row] = p;
    __syncthreads();
    if (tid < H_) vs[tid] = pt[0][tid]+pt[1][tid]+pt[2][tid]+pt[3][tid] + pab[s*H_+tid];
    __syncthreads();
    if (tid < D_) {
      float sc = 0.f;
      for (int h=0;h<H_;++h) sc = fmaf(outs[tid][h], vs[h], sc);
      as_[tid] = sc;
    }
    __syncthreads();
    if (tid == 0) {
      float m = -1e30f;
      for (int t=0;t<D_;++t) m = fmaxf(m, as_[t]);
      float sum = 0.f;
      for (int t=0;t<D_;++t) { float e = __expf(as_[t]-m); as_[t]=e; sum += e; }
      float inv = 1.0f/sum;
      for (int t=0;t<D_;++t) as_[t] *= inv;
    }
    __syncthreads();
    if (tid < H_) {
      float acc = 0.f;
      for (int t=0;t<D_;++t) acc = fmaf(as_[t], outs[t][tid], acc);
      xvec[s*H_+tid] = acc;
    }
  }
}

// ---------------------------------------------------------------- K4: stock GRU over news + attention + bilinear -> feature
__global__ __launch_bounds__(256) void k_stock(
    const float* __restrict__ news, const float* __restrict__ Wih,
    const float* __restrict__ Whh, const float* __restrict__ bih,
    const float* __restrict__ bhh, const float* __restrict__ saW,
    const float* __restrict__ sab, const float* __restrict__ biW,
    const float* __restrict__ bib, const float* __restrict__ xvec,
    float* __restrict__ feat)
{
  const int s = blockIdx.x;
  const int tid = threadIdx.x;
  const int row = tid & 63, q = tid >> 6;
  __shared__ float xs[H_], hs[H_];
  __shared__ float outs[D_][H_+1];
  __shared__ float gsum[128], gxn[64], ghn[64];
  __shared__ float pt[4][H_], vs[H_], as_[D_];
  __shared__ float tv[H_], xv2[H_];
  __shared__ float pmat[H_*H_];

  float wih[64]; float whh[64]; float bihr=0.f, bhhr=0.f;
  if (tid < G3) {
    const float* wp = Wih + ((size_t)s*G3 + tid)*H_;
    const float* hp = Whh + ((size_t)s*G3 + tid)*H_;
    #pragma unroll
    for (int j=0;j<64;++j) { wih[j]=wp[j]; whh[j]=hp[j]; }
    bihr = bih[s*G3+tid]; bhhr = bhh[s*G3+tid];
  }
  if (tid < H_) hs[tid]=0.f;
  __syncthreads();

  for (int d=0; d<D_; ++d) {
    if (tid < H_) xs[tid] = news[((size_t)s*D_ + d)*H_ + tid];
    __syncthreads();
    if (tid < G3) {
      float gx = bihr, gh = bhhr;
      const float4* x4 = reinterpret_cast<const float4*>(xs);
      const float4* h4 = reinterpret_cast<const float4*>(hs);
      #pragma unroll
      for (int j4=0;j4<16;++j4) {
        float4 xv=x4[j4]; float4 hv=h4[j4];
        gx = fmaf(wih[j4*4+0],xv.x,gx); gx = fmaf(wih[j4*4+1],xv.y,gx);
        gx = fmaf(wih[j4*4+2],xv.z,gx); gx = fmaf(wih[j4*4+3],xv.w,gx);
        gh = fmaf(whh[j4*4+0],hv.x,gh); gh = fmaf(whh[j4*4+1],hv.y,gh);
        gh = fmaf(whh[j4*4+2],hv.z,gh); gh = fmaf(whh[j4*4+3],hv.w,gh);
      }
      if (tid < 128) gsum[tid] = gx + gh;
      else { gxn[tid-128] = gx; ghn[tid-128] = gh; }
    }
    __syncthreads();
    if (tid < H_) {
      float r = sigm(gsum[tid]);
      float z = sigm(gsum[64+tid]);
      float n = tanhf(gxn[tid] + r*ghn[tid]);
      float h2 = (1.f-z)*n + z*hs[tid];
      hs[tid]=h2; outs[d][tid]=h2;
    }
    __syncthreads();
  }

  // attention -> tvec
  {
    const float* Wp = saW + ((size_t)s*H_ + row)*H_ + q*16;
    float p = 0.f;
    #pragma unroll
    for (int j=0;j<16;++j) p = fmaf(Wp[j], hs[q*16+j], p);
    pt[q][row] = p;
    __syncthreads();
    if (tid < H_) vs[tid] = pt[0][tid]+pt[1][tid]+pt[2][tid]+pt[3][tid] + sab[s*H_+tid];
    __syncthreads();
    if (tid < D_) {
      float sc = 0.f;
      for (int h=0;h<H_;++h) sc = fmaf(outs[tid][h], vs[h], sc);
      as_[tid] = sc;
    }
    __syncthreads();
    if (tid == 0) {
      float m = -1e30f;
      for (int t=0;t<D_;++t) m = fmaxf(m, as_[t]);
      float sum = 0.f;
      for (int t=0;t<D_;++t) { float e = __expf(as_[t]-m); as_[t]=e; sum += e; }
      float inv = 1.0f/sum;
      for (int t=0;t<D_;++t) as_[t] *= inv;
    }
    __syncthreads();
    if (tid < H_) {
      float acc = 0.f;
      for (int t=0;t<D_;++t) acc = fmaf(as_[t], outs[t][tid], acc);
      tv[tid] = acc;
      xv2[tid] = xvec[s*H_+tid];
    }
    __syncthreads();
  }

  // bilinear: feat_k = tanh( sum_ij tv_i * biW[k,i,j] * xv_j + bib_k )
  for (int e=tid; e<H_*H_; e+=256) pmat[e] = tv[e>>6]*xv2[e&63];
  __syncthreads();
  {
    const float* Wk0 = biW + (size_t)s*H_*H_*H_;
    const int lane = tid & 63, w = tid >> 6;
    const float4* P4 = reinterpret_cast<const float4*>(pmat);
    for (int k = w; k < H_; k += 4) {
      const float4* W4 = reinterpret_cast<const float4*>(Wk0 + (size_t)k*H_*H_);
      float acc = 0.f;
      #pragma unroll 4
      for (int r=0;r<16;++r) {
        float4 wv = W4[r*64+lane];
        float4 pv = P4[r*64+lane];
        acc += wv.x*pv.x + wv.y*pv.y + wv.z*pv.z + wv.w*pv.w;
      }
      #pragma unroll
      for (int off=32; off>0; off>>=1) acc += __shfl_down(acc, off, 64);
      if (lane==0) feat[s*H_+k] = tanhf(acc + bib[s*H_+k]);
    }
  }
}

// ---------------------------------------------------------------- K5: head (out_1, MHA, elu, softmax, loss)
__global__ __launch_bounds__(1024) void k_head(
    const float* __restrict__ feat, const float* __restrict__ blW,
    const float* __restrict__ blb, const float* __restrict__ Wq,
    const float* __restrict__ bq, const float* __restrict__ Wk,
    const float* __restrict__ bk, const float* __restrict__ fcW,
    const float* __restrict__ fcb, const int* __restrict__ label,
    float* __restrict__ Qg, float* __restrict__ Kg, float* __restrict__ scw,
    float* __restrict__ dout)
{
  const int tid = threadIdx.x;
  __shared__ float fs[S_*H_];
  __shared__ float mhs[S_*H_];
  __shared__ float o1[S_*2];
  __shared__ float lt[S_];

  for (int e=tid; e<S_*H_; e+=1024) fs[e] = feat[e];
  __syncthreads();

  if (tid < 2*S_) {
    int s = tid>>1, c = tid&1;
    const float* w = blW + ((size_t)(S_-1)*2 + c)*H_;
    float a = blb[(S_-1)*2 + c];
    for (int h=0;h<H_;++h) a = fmaf(fs[s*H_+h], w[h], a);
    o1[tid] = tanhf(a);
  }
  for (int e=tid; e<S_*H_; e+=1024) {
    int s = e>>6, o = e&63;
    float aq = bq[o], ak = bk[o];
    const float* wq = Wq + o*H_;
    const float* wk = Wk + o*H_;
    for (int h=0;h<H_;++h) { float f = fs[s*H_+h]; aq = fmaf(f, wq[h], aq); ak = fmaf(f, wk[h], ak); }
    Qg[e]=aq; Kg[e]=ak;
  }
  __syncthreads();

  if (tid < 4*S_) {
    int s = tid % S_, hd = tid / S_;
    const float* qr = Qg + s*H_ + hd*16;
    float m = -1e30f;
    for (int t=0;t<S_;++t) {
      const float* kr = Kg + t*H_ + hd*16;
      float sc=0.f;
      #pragma unroll
      for (int d2=0; d2<16; ++d2) sc = fmaf(qr[d2], kr[d2], sc);
      sc *= 0.25f;
      scw[(size_t)tid*S_+t]=sc;
      m = fmaxf(m, sc);
    }
    float sum=0.f;
    for (int t=0;t<S_;++t) { float e=__expf(scw[(size_t)tid*S_+t]-m); scw[(size_t)tid*S_+t]=e; sum+=e; }
    float inv=1.f/sum;
    float acc[16];
    #pragma unroll
    for (int d2=0;d2<16;++d2) acc[d2]=0.f;
    for (int t=0;t<S_;++t) {
      float a = scw[(size_t)tid*S_+t]*inv;
      #pragma unroll
      for (int d2=0;d2<16;++d2) acc[d2] = fmaf(a, fs[t*H_ + hd*16 + d2], acc[d2]);
    }
    #pragma unroll
    for (int d2=0;d2<16;++d2) mhs[s*H_ + hd*16 + d2] = acc[d2];
  }
  __syncthreads();

  if (tid < S_) {
    int s = tid;
    float e0 = fcb[0], e1 = fcb[1];
    for (int h=0;h<H_;++h) { float mv = mhs[s*H_+h]; e0 = fmaf(mv, fcW[h], e0); e1 = fmaf(mv, fcW[H_+h], e1); }
    float x0 = e0>0.f?e0:(__expf(e0)-1.f);
    float x1 = e1>0.f?e1:(__expf(e1)-1.f);
    float y0 = x0 + o1[s*2], y1 = x1 + o1[s*2+1];
    float mm = fmaxf(y0,y1);
    float p0 = __expf(y0-mm), p1=__expf(y1-mm);
    float is = 1.f/(p0+p1);
    float out0 = p0*is, out1 = p1*is;
    float m2 = fmaxf(out0,out1);
    float lse = m2 + logf(__expf(out0-m2)+__expf(out1-m2));
    float ol = (label[s]!=0) ? out1 : out0;
    lt[s] = lse - ol;
    dout[1 + s*2]   = out0;
    dout[2 + s*2]   = out1;
  }
  __syncthreads();
  if (tid==0) {
    float sum=0.f;
    for (int s=0;s<S_;++s) sum += lt[s];
    dout[0] = sum * (1.0f/(float)S_);
  }
}

// ---------------------------------------------------------------- launch
extern "C" void kernel_launch(void* const* d_in, const int* in_sizes, int n_in,
                              void* d_out, int out_size, void* d_ws, size_t ws_size,
                              hipStream_t stream) {
  const float* pg_Wih  = (const float*)d_in[0];
  const float* pg_Whh  = (const float*)d_in[1];
  const float* pg_bih  = (const float*)d_in[2];
  const float* pg_bhh  = (const float*)d_in[3];
  const float* pa_W    = (const float*)d_in[4];
  const float* pa_b    = (const float*)d_in[5];
  const float* tl_Wall = (const float*)d_in[6];
  const float* tl_bWall= (const float*)d_in[7];
  const float* tl_Uall = (const float*)d_in[8];
  const float* tl_bUall= (const float*)d_in[9];
  const float* tl_Wd   = (const float*)d_in[10];
  const float* tl_bd   = (const float*)d_in[11];
  const float* ta_W    = (const float*)d_in[12];
  const float* ta_b    = (const float*)d_in[13];
  const float* sg_Wih  = (const float*)d_in[14];
  const float* sg_Whh  = (const float*)d_in[15];
  const float* sg_bih  = (const float*)d_in[16];
  const float* sg_bhh  = (const float*)d_in[17];
  const float* sa_W    = (const float*)d_in[18];
  const float* sa_b    = (const float*)d_in[19];
  const float* bi_W    = (const float*)d_in[20];
  const float* bi_b    = (const float*)d_in[21];
  const float* bl_W    = (const float*)d_in[22];
  const float* bl_b    = (const float*)d_in[23];
  const float* mha_Wq  = (const float*)d_in[24];
  const float* mha_bq  = (const float*)d_in[25];
  const float* mha_Wk  = (const float*)d_in[26];
  const float* mha_bk  = (const float*)d_in[27];
  const float* fc_W    = (const float*)d_in[28];
  const float* fc_b    = (const float*)d_in[29];
  const float* text    = (const float*)d_in[30];
  const float* price   = (const float*)d_in[31];
  const float* tstamps = (const float*)d_in[32];
  const int*   label   = (const int*)d_in[33];
  (void)in_sizes; (void)n_in; (void)out_size; (void)ws_size;

  float* ws   = (float*)d_ws;
  float* GX   = ws;                          // 100*1200*256 = 30,720,000
  float* news = GX   + (size_t)S_*M_*G4;     // 192,000
  float* xvec = news + (size_t)S_*D_*H_;     // 6,400
  float* feat = xvec + (size_t)S_*H_;        // 6,400
  float* Qg   = feat + (size_t)S_*H_;        // 6,400
  float* Kg   = Qg   + (size_t)S_*H_;        // 6,400
  float* scw  = Kg   + (size_t)S_*H_;        // 40,000
  float* dout = (float*)d_out;

  dim3 g1((M_+BM-1)/BM, G4/BN, S_);
  k_text_gemm<<<g1, 256, 0, stream>>>(text, tl_Wall, tl_bWall, tl_bUall, GX);
  k_timelstm<<<S_*D_, 256, 0, stream>>>(GX, tl_Uall, tl_Wd, tl_bd, ta_W, ta_b, tstamps, news);
  k_price_gru<<<S_, 256, 0, stream>>>(price, pg_Wih, pg_Whh, pg_bih, pg_bhh, pa_W, pa_b, xvec);
  k_stock<<<S_, 256, 0, stream>>>(news, sg_Wih, sg_Whh, sg_bih, sg_bhh, sa_W, sa_b, bi_W, bi_b, xvec, feat);
  k_head<<<1, 1024, 0, stream>>>(feat, bl_W, bl_b, mha_Wq, mha_bq, mha_Wk, mha_bk, fc_W, fc_b, label, Qg, Kg, scw, dout);
}

// Round 2
// 660.288 us; speedup vs baseline: 1.3155x; 1.3155x over previous
//
#include <hip/hip_runtime.h>
#include <math.h>

#define S_  100
#define D_  30
#define T_  40
#define FT_ 512
#define FP_ 3
#define H_  64
#define G3  192
#define G4  256
#define M_  (D_*T_)   // 1200

typedef __attribute__((ext_vector_type(8))) short short8_t;
typedef __attribute__((ext_vector_type(4))) float f32x4;

__device__ __forceinline__ float sigm(float x){ return 1.0f/(1.0f+__expf(-x)); }

__device__ __forceinline__ short f2bf(float f){
  unsigned u = __builtin_bit_cast(unsigned, f);
  u += 0x7FFFu + ((u>>16)&1u);
  return (short)(u>>16);
}

// ---------------------------------------------------------------- K1: GX = Wall @ x + bWall + bUall  (bf16 MFMA)
#define BMt 128
#define BNt 64
#define BKt 64
#define LDT 72   // padded shorts per LDS row (144 B: 16B-aligned, 2-way max bank alias)

__global__ __launch_bounds__(256) void k_text_gemm(
    const float* __restrict__ text, const float* __restrict__ Wall,
    const float* __restrict__ bW, const float* __restrict__ bU,
    float* __restrict__ GX)
{
  const int s  = blockIdx.z;
  const int m0 = blockIdx.x * BMt;
  const int n0 = blockIdx.y * BNt;
  const int tid  = threadIdx.x;
  const int lane = tid & 63;
  const int wave = tid >> 6;
  const int wm = wave >> 1, wn = wave & 1;   // 2x2 wave grid; wave tile 64x32

  __shared__ short As[BMt][LDT];
  __shared__ short Bs[BNt][LDT];

  const float* X = text + (size_t)s*((size_t)M_*FT_);
  const float* W = Wall + (size_t)s*((size_t)G4*FT_);

  f32x4 acc[4][2];
  #pragma unroll
  for (int i=0;i<4;++i)
    #pragma unroll
    for (int j=0;j<2;++j)
      acc[i][j] = (f32x4)(0.f);

  // staging mapping
  const int ra = tid >> 1;          // 0..127 (A row)
  const int ka = (tid & 1) * 32;    // 0 / 32 (A k-offset, fp32 elems)
  const int rb = tid >> 2;          // 0..63  (B row)
  const int kb = (tid & 3) * 16;    // 0..48  (B k-offset)

  const int fr = lane & 15;         // fragment row/col index
  const int fk = (lane >> 4) * 8;   // fragment k offset

  for (int k0 = 0; k0 < FT_; k0 += BKt) {
    // stage A (128 x 64 fp32 -> bf16)
    {
      const int m = m0 + ra;
      if (m < M_) {
        const float* src = X + (size_t)m*FT_ + k0 + ka;
        #pragma unroll
        for (int j=0;j<4;++j) {
          float4 v0 = *reinterpret_cast<const float4*>(src + j*8);
          float4 v1 = *reinterpret_cast<const float4*>(src + j*8 + 4);
          short8_t o;
          o[0]=f2bf(v0.x); o[1]=f2bf(v0.y); o[2]=f2bf(v0.z); o[3]=f2bf(v0.w);
          o[4]=f2bf(v1.x); o[5]=f2bf(v1.y); o[6]=f2bf(v1.z); o[7]=f2bf(v1.w);
          *reinterpret_cast<short8_t*>(&As[ra][ka + j*8]) = o;
        }
      } else {
        #pragma unroll
        for (int j=0;j<4;++j)
          *reinterpret_cast<short8_t*>(&As[ra][ka + j*8]) = (short8_t)(short)0;
      }
    }
    // stage B (64 x 64 fp32 -> bf16)
    {
      const float* src = W + (size_t)(n0 + rb)*FT_ + k0 + kb;
      #pragma unroll
      for (int j=0;j<2;++j) {
        float4 v0 = *reinterpret_cast<const float4*>(src + j*8);
        float4 v1 = *reinterpret_cast<const float4*>(src + j*8 + 4);
        short8_t o;
        o[0]=f2bf(v0.x); o[1]=f2bf(v0.y); o[2]=f2bf(v0.z); o[3]=f2bf(v0.w);
        o[4]=f2bf(v1.x); o[5]=f2bf(v1.y); o[6]=f2bf(v1.z); o[7]=f2bf(v1.w);
        *reinterpret_cast<short8_t*>(&Bs[rb][kb + j*8]) = o;
      }
    }
    __syncthreads();

    #pragma unroll
    for (int ks=0; ks<BKt; ks+=32) {
      short8_t a[4], b[2];
      #pragma unroll
      for (int i=0;i<4;++i)
        a[i] = *reinterpret_cast<const short8_t*>(&As[wm*64 + i*16 + fr][ks + fk]);
      #pragma unroll
      for (int j=0;j<2;++j)
        b[j] = *reinterpret_cast<const short8_t*>(&Bs[wn*32 + j*16 + fr][ks + fk]);
      #pragma unroll
      for (int i=0;i<4;++i)
        #pragma unroll
        for (int j=0;j<2;++j)
          acc[i][j] = __builtin_amdgcn_mfma_f32_16x16x32_bf16(a[i], b[j], acc[i][j], 0,0,0);
    }
    __syncthreads();
  }

  // epilogue: C/D layout col=lane&15, row=(lane>>4)*4+reg
  const int cn = lane & 15;
  const int rm = (lane >> 4) * 4;
  #pragma unroll
  for (int j=0;j<2;++j) {
    const int n = n0 + wn*32 + j*16 + cn;
    const float bias = bW[s*G4+n] + bU[s*G4+n];
    #pragma unroll
    for (int i=0;i<4;++i) {
      const int mbase = m0 + wm*64 + i*16 + rm;
      #pragma unroll
      for (int r=0;r<4;++r) {
        const int m = mbase + r;
        if (m < M_) GX[((size_t)s*M_ + m)*G4 + n] = acc[i][j][r] + bias;
      }
    }
  }
}

// ---------------------------------------------------------------- K2: TimeLSTM + day attention -> news
__global__ __launch_bounds__(256) void k_timelstm(
    const float* __restrict__ GX, const float* __restrict__ Uall,
    const float* __restrict__ Wd, const float* __restrict__ bd,
    const float* __restrict__ taW, const float* __restrict__ tab,
    const float* __restrict__ ts, float* __restrict__ news)
{
  const int blk = blockIdx.x;
  const int s = blk / D_;
  const int d = blk % D_;
  const int tid = threadIdx.x;
  const int row = tid & 63, q = tid >> 6;
  __shared__ float hs[H_], cs[H_], gs[G4], pt[4][H_];
  __shared__ float outs[T_][H_+1];
  __shared__ float vs[H_], as_[T_];

  float u[64];
  {
    const float* Up = Uall + ((size_t)s*G4 + tid)*H_;
    #pragma unroll
    for (int j=0;j<64;++j) u[j] = Up[j];
  }
  float wd[16];
  {
    const float* Wp = Wd + ((size_t)s*H_ + row)*H_ + q*16;
    #pragma unroll
    for (int j=0;j<16;++j) wd[j] = Wp[j];
  }
  const float bdr = bd[s*H_ + row];
  if (tid < H_) { hs[tid]=0.f; cs[tid]=0.f; }
  __syncthreads();

  const float* gxp = GX + ((size_t)s*M_ + d*T_)*G4;
  const float* tsp = ts + ((size_t)s*D_ + d)*T_;

  for (int t=0; t<T_; ++t) {
    float p = 0.f;
    #pragma unroll
    for (int j=0;j<16;++j) p = fmaf(wd[j], cs[q*16+j], p);
    pt[q][row] = p;

    float g = gxp[t*G4 + tid];
    const float4* h4 = reinterpret_cast<const float4*>(hs);
    #pragma unroll
    for (int j4=0;j4<16;++j4) {
      float4 hv = h4[j4];
      g = fmaf(u[j4*4+0], hv.x, g);
      g = fmaf(u[j4*4+1], hv.y, g);
      g = fmaf(u[j4*4+2], hv.z, g);
      g = fmaf(u[j4*4+3], hv.w, g);
    }
    gs[tid] = sigm(g);
    __syncthreads();
    if (tid < H_) {
      float cs1 = tanhf(pt[0][tid]+pt[1][tid]+pt[2][tid]+pt[3][tid] + bdr);
      float tv = tsp[t];
      float cadj = cs[tid] - cs1 + cs1*tv;
      float c2 = gs[tid]*cadj + gs[64+tid]*gs[192+tid];
      float h2 = gs[128+tid]*tanhf(c2);
      cs[tid] = c2; hs[tid] = h2; outs[t][tid] = h2;
    }
    __syncthreads();
  }

  // attention: v = taW@h_last + tab ; scores = outs@v ; softmax ; news = a@outs
  {
    const float* Wp = taW + ((size_t)s*H_ + row)*H_ + q*16;
    float p = 0.f;
    #pragma unroll
    for (int j=0;j<16;++j) p = fmaf(Wp[j], hs[q*16+j], p);
    pt[q][row] = p;
    __syncthreads();
    if (tid < H_) vs[tid] = pt[0][tid]+pt[1][tid]+pt[2][tid]+pt[3][tid] + tab[s*H_+tid];
    __syncthreads();
    if (tid < T_) {
      float sc = 0.f;
      for (int h=0;h<H_;++h) sc = fmaf(outs[tid][h], vs[h], sc);
      as_[tid] = sc;
    }
    __syncthreads();
    if (tid == 0) {
      float m = -1e30f;
      for (int t=0;t<T_;++t) m = fmaxf(m, as_[t]);
      float sum = 0.f;
      for (int t=0;t<T_;++t) { float e = __expf(as_[t]-m); as_[t]=e; sum += e; }
      float inv = 1.0f/sum;
      for (int t=0;t<T_;++t) as_[t] *= inv;
    }
    __syncthreads();
    if (tid < H_) {
      float acc = 0.f;
      for (int t=0;t<T_;++t) acc = fmaf(as_[t], outs[t][tid], acc);
      news[((size_t)s*D_ + d)*H_ + tid] = acc;
    }
  }
}

// ---------------------------------------------------------------- K3: price GRU + attention -> xvec
__global__ __launch_bounds__(256) void k_price_gru(
    const float* __restrict__ price, const float* __restrict__ Wih,
    const float* __restrict__ Whh, const float* __restrict__ bih,
    const float* __restrict__ bhh, const float* __restrict__ paW,
    const float* __restrict__ pab, float* __restrict__ xvec)
{
  const int s = blockIdx.x;
  const int tid = threadIdx.x;
  const int row = tid & 63, q = tid >> 6;
  __shared__ float hs[H_];
  __shared__ float outs[D_][H_+1];
  __shared__ float gsum[128], gxn[64], ghn[64];
  __shared__ float pt[4][H_], vs[H_], as_[D_];

  float wih[3]; float whh[64]; float bihr=0.f, bhhr=0.f;
  if (tid < G3) {
    const float* wp = Wih + ((size_t)s*G3 + tid)*FP_;
    wih[0]=wp[0]; wih[1]=wp[1]; wih[2]=wp[2];
    const float* hp = Whh + ((size_t)s*G3 + tid)*H_;
    #pragma unroll
    for (int j=0;j<64;++j) whh[j]=hp[j];
    bihr = bih[s*G3+tid]; bhhr = bhh[s*G3+tid];
  }
  if (tid < H_) hs[tid]=0.f;
  __syncthreads();

  for (int d=0; d<D_; ++d) {
    const float* pp = price + ((size_t)s*D_ + d)*FP_;
    float p0=pp[0], p1=pp[1], p2=pp[2];
    if (tid < G3) {
      float gx = bihr + wih[0]*p0 + wih[1]*p1 + wih[2]*p2;
      float gh = bhhr;
      const float4* h4 = reinterpret_cast<const float4*>(hs);
      #pragma unroll
      for (int j4=0;j4<16;++j4) {
        float4 hv=h4[j4];
        gh = fmaf(whh[j4*4+0],hv.x,gh);
        gh = fmaf(whh[j4*4+1],hv.y,gh);
        gh = fmaf(whh[j4*4+2],hv.z,gh);
        gh = fmaf(whh[j4*4+3],hv.w,gh);
      }
      if (tid < 128) gsum[tid] = gx + gh;
      else { gxn[tid-128] = gx; ghn[tid-128] = gh; }
    }
    __syncthreads();
    if (tid < H_) {
      float r = sigm(gsum[tid]);
      float z = sigm(gsum[64+tid]);
      float n = tanhf(gxn[tid] + r*ghn[tid]);
      float h2 = (1.f-z)*n + z*hs[tid];
      hs[tid]=h2; outs[d][tid]=h2;
    }
    __syncthreads();
  }

  {
    const float* Wp = paW + ((size_t)s*H_ + row)*H_ + q*16;
    float p = 0.f;
    #pragma unroll
    for (int j=0;j<16;++j) p = fmaf(Wp[j], hs[q*16+j], p);
    pt[q][row] = p;
    __syncthreads();
    if (tid < H_) vs[tid] = pt[0][tid]+pt[1][tid]+pt[2][tid]+pt[3][tid] + pab[s*H_+tid];
    __syncthreads();
    if (tid < D_) {
      float sc = 0.f;
      for (int h=0;h<H_;++h) sc = fmaf(outs[tid][h], vs[h], sc);
      as_[tid] = sc;
    }
    __syncthreads();
    if (tid == 0) {
      float m = -1e30f;
      for (int t=0;t<D_;++t) m = fmaxf(m, as_[t]);
      float sum = 0.f;
      for (int t=0;t<D_;++t) { float e = __expf(as_[t]-m); as_[t]=e; sum += e; }
      float inv = 1.0f/sum;
      for (int t=0;t<D_;++t) as_[t] *= inv;
    }
    __syncthreads();
    if (tid < H_) {
      float acc = 0.f;
      for (int t=0;t<D_;++t) acc = fmaf(as_[t], outs[t][tid], acc);
      xvec[s*H_+tid] = acc;
    }
  }
}

// ---------------------------------------------------------------- K4: stock GRU over news + attention + bilinear -> feature
__global__ __launch_bounds__(256) void k_stock(
    const float* __restrict__ news, const float* __restrict__ Wih,
    const float* __restrict__ Whh, const float* __restrict__ bih,
    const float* __restrict__ bhh, const float* __restrict__ saW,
    const float* __restrict__ sab, const float* __restrict__ biW,
    const float* __restrict__ bib, const float* __restrict__ xvec,
    float* __restrict__ feat)
{
  const int s = blockIdx.x;
  const int tid = threadIdx.x;
  const int row = tid & 63, q = tid >> 6;
  __shared__ float xs[H_], hs[H_];
  __shared__ float outs[D_][H_+1];
  __shared__ float gsum[128], gxn[64], ghn[64];
  __shared__ float pt[4][H_], vs[H_], as_[D_];
  __shared__ float tv[H_], xv2[H_];
  __shared__ float pmat[H_*H_];

  float wih[64]; float whh[64]; float bihr=0.f, bhhr=0.f;
  if (tid < G3) {
    const float* wp = Wih + ((size_t)s*G3 + tid)*H_;
    const float* hp = Whh + ((size_t)s*G3 + tid)*H_;
    #pragma unroll
    for (int j=0;j<64;++j) { wih[j]=wp[j]; whh[j]=hp[j]; }
    bihr = bih[s*G3+tid]; bhhr = bhh[s*G3+tid];
  }
  if (tid < H_) hs[tid]=0.f;
  __syncthreads();

  for (int d=0; d<D_; ++d) {
    if (tid < H_) xs[tid] = news[((size_t)s*D_ + d)*H_ + tid];
    __syncthreads();
    if (tid < G3) {
      float gx = bihr, gh = bhhr;
      const float4* x4 = reinterpret_cast<const float4*>(xs);
      const float4* h4 = reinterpret_cast<const float4*>(hs);
      #pragma unroll
      for (int j4=0;j4<16;++j4) {
        float4 xv=x4[j4]; float4 hv=h4[j4];
        gx = fmaf(wih[j4*4+0],xv.x,gx); gx = fmaf(wih[j4*4+1],xv.y,gx);
        gx = fmaf(wih[j4*4+2],xv.z,gx); gx = fmaf(wih[j4*4+3],xv.w,gx);
        gh = fmaf(whh[j4*4+0],hv.x,gh); gh = fmaf(whh[j4*4+1],hv.y,gh);
        gh = fmaf(whh[j4*4+2],hv.z,gh); gh = fmaf(whh[j4*4+3],hv.w,gh);
      }
      if (tid < 128) gsum[tid] = gx + gh;
      else { gxn[tid-128] = gx; ghn[tid-128] = gh; }
    }
    __syncthreads();
    if (tid < H_) {
      float r = sigm(gsum[tid]);
      float z = sigm(gsum[64+tid]);
      float n = tanhf(gxn[tid] + r*ghn[tid]);
      float h2 = (1.f-z)*n + z*hs[tid];
      hs[tid]=h2; outs[d][tid]=h2;
    }
    __syncthreads();
  }

  // attention -> tvec
  {
    const float* Wp = saW + ((size_t)s*H_ + row)*H_ + q*16;
    float p = 0.f;
    #pragma unroll
    for (int j=0;j<16;++j) p = fmaf(Wp[j], hs[q*16+j], p);
    pt[q][row] = p;
    __syncthreads();
    if (tid < H_) vs[tid] = pt[0][tid]+pt[1][tid]+pt[2][tid]+pt[3][tid] + sab[s*H_+tid];
    __syncthreads();
    if (tid < D_) {
      float sc = 0.f;
      for (int h=0;h<H_;++h) sc = fmaf(outs[tid][h], vs[h], sc);
      as_[tid] = sc;
    }
    __syncthreads();
    if (tid == 0) {
      float m = -1e30f;
      for (int t=0;t<D_;++t) m = fmaxf(m, as_[t]);
      float sum = 0.f;
      for (int t=0;t<D_;++t) { float e = __expf(as_[t]-m); as_[t]=e; sum += e; }
      float inv = 1.0f/sum;
      for (int t=0;t<D_;++t) as_[t] *= inv;
    }
    __syncthreads();
    if (tid < H_) {
      float acc = 0.f;
      for (int t=0;t<D_;++t) acc = fmaf(as_[t], outs[t][tid], acc);
      tv[tid] = acc;
      xv2[tid] = xvec[s*H_+tid];
    }
    __syncthreads();
  }

  // bilinear: feat_k = tanh( sum_ij tv_i * biW[k,i,j] * xv_j + bib_k )
  for (int e=tid; e<H_*H_; e+=256) pmat[e] = tv[e>>6]*xv2[e&63];
  __syncthreads();
  {
    const float* Wk0 = biW + (size_t)s*H_*H_*H_;
    const int lane = tid & 63, w = tid >> 6;
    const float4* P4 = reinterpret_cast<const float4*>(pmat);
    for (int k = w; k < H_; k += 4) {
      const float4* W4 = reinterpret_cast<const float4*>(Wk0 + (size_t)k*H_*H_);
      float acc = 0.f;
      #pragma unroll 4
      for (int r=0;r<16;++r) {
        float4 wv = W4[r*64+lane];
        float4 pv = P4[r*64+lane];
        acc += wv.x*pv.x + wv.y*pv.y + wv.z*pv.z + wv.w*pv.w;
      }
      #pragma unroll
      for (int off=32; off>0; off>>=1) acc += __shfl_down(acc, off, 64);
      if (lane==0) feat[s*H_+k] = tanhf(acc + bib[s*H_+k]);
    }
  }
}

// ---------------------------------------------------------------- K5: head (out_1, MHA, elu, softmax, loss)
__global__ __launch_bounds__(1024) void k_head(
    const float* __restrict__ feat, const float* __restrict__ blW,
    const float* __restrict__ blb, const float* __restrict__ Wq,
    const float* __restrict__ bq, const float* __restrict__ Wk,
    const float* __restrict__ bk, const float* __restrict__ fcW,
    const float* __restrict__ fcb, const int* __restrict__ label,
    float* __restrict__ Qg, float* __restrict__ Kg, float* __restrict__ scw,
    float* __restrict__ dout)
{
  const int tid = threadIdx.x;
  __shared__ float fs[S_*H_];
  __shared__ float mhs[S_*H_];
  __shared__ float o1[S_*2];
  __shared__ float lt[S_];

  for (int e=tid; e<S_*H_; e+=1024) fs[e] = feat[e];
  __syncthreads();

  if (tid < 2*S_) {
    int s = tid>>1, c = tid&1;
    const float* w = blW + ((size_t)(S_-1)*2 + c)*H_;
    float a = blb[(S_-1)*2 + c];
    for (int h=0;h<H_;++h) a = fmaf(fs[s*H_+h], w[h], a);
    o1[tid] = tanhf(a);
  }
  for (int e=tid; e<S_*H_; e+=1024) {
    int s = e>>6, o = e&63;
    float aq = bq[o], ak = bk[o];
    const float* wq = Wq + o*H_;
    const float* wk = Wk + o*H_;
    for (int h=0;h<H_;++h) { float f = fs[s*H_+h]; aq = fmaf(f, wq[h], aq); ak = fmaf(f, wk[h], ak); }
    Qg[e]=aq; Kg[e]=ak;
  }
  __syncthreads();

  if (tid < 4*S_) {
    int s = tid % S_, hd = tid / S_;
    const float* qr = Qg + s*H_ + hd*16;
    float m = -1e30f;
    for (int t=0;t<S_;++t) {
      const float* kr = Kg + t*H_ + hd*16;
      float sc=0.f;
      #pragma unroll
      for (int d2=0; d2<16; ++d2) sc = fmaf(qr[d2], kr[d2], sc);
      sc *= 0.25f;
      scw[(size_t)tid*S_+t]=sc;
      m = fmaxf(m, sc);
    }
    float sum=0.f;
    for (int t=0;t<S_;++t) { float e=__expf(scw[(size_t)tid*S_+t]-m); scw[(size_t)tid*S_+t]=e; sum+=e; }
    float inv=1.f/sum;
    float acc[16];
    #pragma unroll
    for (int d2=0;d2<16;++d2) acc[d2]=0.f;
    for (int t=0;t<S_;++t) {
      float a = scw[(size_t)tid*S_+t]*inv;
      #pragma unroll
      for (int d2=0;d2<16;++d2) acc[d2] = fmaf(a, fs[t*H_ + hd*16 + d2], acc[d2]);
    }
    #pragma unroll
    for (int d2=0;d2<16;++d2) mhs[s*H_ + hd*16 + d2] = acc[d2];
  }
  __syncthreads();

  if (tid < S_) {
    int s = tid;
    float e0 = fcb[0], e1 = fcb[1];
    for (int h=0;h<H_;++h) { float mv = mhs[s*H_+h]; e0 = fmaf(mv, fcW[h], e0); e1 = fmaf(mv, fcW[H_+h], e1); }
    float x0 = e0>0.f?e0:(__expf(e0)-1.f);
    float x1 = e1>0.f?e1:(__expf(e1)-1.f);
    float y0 = x0 + o1[s*2], y1 = x1 + o1[s*2+1];
    float mm = fmaxf(y0,y1);
    float p0 = __expf(y0-mm), p1=__expf(y1-mm);
    float is = 1.f/(p0+p1);
    float out0 = p0*is, out1 = p1*is;
    float m2 = fmaxf(out0,out1);
    float lse = m2 + logf(__expf(out0-m2)+__expf(out1-m2));
    float ol = (label[s]!=0) ? out1 : out0;
    lt[s] = lse - ol;
    dout[1 + s*2]   = out0;
    dout[2 + s*2]   = out1;
  }
  __syncthreads();
  if (tid==0) {
    float sum=0.f;
    for (int s=0;s<S_;++s) sum += lt[s];
    dout[0] = sum * (1.0f/(float)S_);
  }
}

// ---------------------------------------------------------------- launch
extern "C" void kernel_launch(void* const* d_in, const int* in_sizes, int n_in,
                              void* d_out, int out_size, void* d_ws, size_t ws_size,
                              hipStream_t stream) {
  const float* pg_Wih  = (const float*)d_in[0];
  const float* pg_Whh  = (const float*)d_in[1];
  const float* pg_bih  = (const float*)d_in[2];
  const float* pg_bhh  = (const float*)d_in[3];
  const float* pa_W    = (const float*)d_in[4];
  const float* pa_b    = (const float*)d_in[5];
  const float* tl_Wall = (const float*)d_in[6];
  const float* tl_bWall= (const float*)d_in[7];
  const float* tl_Uall = (const float*)d_in[8];
  const float* tl_bUall= (const float*)d_in[9];
  const float* tl_Wd   = (const float*)d_in[10];
  const float* tl_bd   = (const float*)d_in[11];
  const float* ta_W    = (const float*)d_in[12];
  const float* ta_b    = (const float*)d_in[13];
  const float* sg_Wih  = (const float*)d_in[14];
  const float* sg_Whh  = (const float*)d_in[15];
  const float* sg_bih  = (const float*)d_in[16];
  const float* sg_bhh  = (const float*)d_in[17];
  const float* sa_W    = (const float*)d_in[18];
  const float* sa_b    = (const float*)d_in[19];
  const float* bi_W    = (const float*)d_in[20];
  const float* bi_b    = (const float*)d_in[21];
  const float* bl_W    = (const float*)d_in[22];
  const float* bl_b    = (const float*)d_in[23];
  const float* mha_Wq  = (const float*)d_in[24];
  const float* mha_bq  = (const float*)d_in[25];
  const float* mha_Wk  = (const float*)d_in[26];
  const float* mha_bk  = (const float*)d_in[27];
  const float* fc_W    = (const float*)d_in[28];
  const float* fc_b    = (const float*)d_in[29];
  const float* text    = (const float*)d_in[30];
  const float* price   = (const float*)d_in[31];
  const float* tstamps = (const float*)d_in[32];
  const int*   label   = (const int*)d_in[33];
  (void)in_sizes; (void)n_in; (void)out_size; (void)ws_size;

  float* ws   = (float*)d_ws;
  float* GX   = ws;                          // 100*1200*256 = 30,720,000
  float* news = GX   + (size_t)S_*M_*G4;     // 192,000
  float* xvec = news + (size_t)S_*D_*H_;     // 6,400
  float* feat = xvec + (size_t)S_*H_;        // 6,400
  float* Qg   = feat + (size_t)S_*H_;        // 6,400
  float* Kg   = Qg   + (size_t)S_*H_;        // 6,400
  float* scw  = Kg   + (size_t)S_*H_;        // 40,000
  float* dout = (float*)d_out;

  dim3 g1((M_+BMt-1)/BMt, G4/BNt, S_);
  k_text_gemm<<<g1, 256, 0, stream>>>(text, tl_Wall, tl_bWall, tl_bUall, GX);
  k_timelstm<<<S_*D_, 256, 0, stream>>>(GX, tl_Uall, tl_Wd, tl_bd, ta_W, ta_b, tstamps, news);
  k_price_gru<<<S_, 256, 0, stream>>>(price, pg_Wih, pg_Whh, pg_bih, pg_bhh, pa_W, pa_b, xvec);
  k_stock<<<S_, 256, 0, stream>>>(news, sg_Wih, sg_Whh, sg_bih, sg_bhh, sa_W, sa_b, bi_W, bi_b, xvec, feat);
  k_head<<<1, 1024, 0, stream>>>(feat, bl_W, bl_b, mha_Wq, mha_bq, mha_Wk, mha_bk, fc_W, fc_b, label, Qg, Kg, scw, dout);
}

// Round 3
// 595.318 us; speedup vs baseline: 1.4590x; 1.1091x over previous
//
#include <hip/hip_runtime.h>
#include <math.h>

#define S_  100
#define D_  30
#define T_  40
#define FT_ 512
#define FP_ 3
#define H_  64
#define G3  192
#define G4  256
#define M_  (D_*T_)   // 1200

typedef __attribute__((ext_vector_type(8))) short short8_t;
typedef __attribute__((ext_vector_type(4))) short short4_t;
typedef __attribute__((ext_vector_type(4))) float f32x4;

__device__ __forceinline__ float sigm(float x){ return 1.0f/(1.0f+__expf(-x)); }

__device__ __forceinline__ short f2bf(float f){
  unsigned u = __builtin_bit_cast(unsigned, f);
  u += 0x7FFFu + ((u>>16)&1u);
  return (short)(u>>16);
}

// ---------------------------------------------------------------- K0: Wall fp32 -> bf16 (once; reused 30x per stock)
__global__ __launch_bounds__(256) void k_conv_wall(
    const float* __restrict__ in, short* __restrict__ out)
{
  const int n4 = (S_*G4*FT_) / 4;   // 3,276,800 float4 groups
  for (int i = blockIdx.x*256 + threadIdx.x; i < n4; i += gridDim.x*256) {
    float4 v = *reinterpret_cast<const float4*>(in + (size_t)i*4);
    short4_t o;
    o[0]=f2bf(v.x); o[1]=f2bf(v.y); o[2]=f2bf(v.z); o[3]=f2bf(v.w);
    *reinterpret_cast<short4_t*>(out + (size_t)i*4) = o;
  }
}

// ---------------------------------------------------------------- K1: fused text-GEMM (MFMA) + TimeLSTM + day attention -> news
// Per block: one (s,d). Phase 1: GX[40][256] = text(40x512) @ Wall^T via bf16 MFMA.
// Phase 2: 40-step TimeLSTM recurrence + attention, GX read from LDS.
// LDS union: phase1 As(49920)+Bs(20480)=70400; phase2 GXs(42240)+outs(10400)+state(~3KB) aliased.
#define SMEM_BYTES 70400

__global__ __launch_bounds__(256, 2) void k_fused_text(
    const float* __restrict__ text, const short* __restrict__ wallbf,
    const float* __restrict__ bW, const float* __restrict__ bU,
    const float* __restrict__ Uall,
    const float* __restrict__ Wd, const float* __restrict__ bd,
    const float* __restrict__ taW, const float* __restrict__ tab,
    const float* __restrict__ ts, float* __restrict__ news)
{
  __shared__ __align__(16) char smem[SMEM_BYTES];
  short (*As)[520] = (short(*)[520])smem;                 // 48 x 520 shorts = 49920 B
  short (*Bs)[40]  = (short(*)[40])(smem + 49920);        // 256 x 40 shorts = 20480 B
  float (*GXs)[264] = (float(*)[264])smem;                // 40 x 264 f32 = 42240 B (aliases As)
  float (*outs)[65] = (float(*)[65])(smem + 42240);       // 40 x 65 f32 = 10400 B -> 52640
  float* hs = (float*)(smem + 52640);                     // 64
  float* cs = hs + 64;                                    // 64
  float* gs = cs + 64;                                    // 256
  float (*pt)[64] = (float(*)[64])(gs + 256);             // 4 x 64
  float* vs  = (float*)(pt + 4);                          // 64
  float* as_ = vs + 64;                                   // 40  (ends 55616 < 70400)

  const int blk = blockIdx.x;
  const int s = blk / D_;
  const int d = blk % D_;
  const int tid  = threadIdx.x;
  const int lane = tid & 63;
  const int wave = tid >> 6;

  // ---------------- Phase 1: GEMM ----------------
  // stage A: text[s][d][0..39][0..511] fp32 -> bf16 LDS
  const float* X = text + ((size_t)s*D_ + d) * ((size_t)T_*FT_);
  #pragma unroll
  for (int i=0;i<20;++i) {
    int idx = tid + 256*i;          // 5120 float4s total
    int r = idx >> 7;               // 128 float4 per row
    int c = (idx & 127) << 2;
    float4 v = *reinterpret_cast<const float4*>(X + (size_t)r*FT_ + c);
    short4_t o;
    o[0]=f2bf(v.x); o[1]=f2bf(v.y); o[2]=f2bf(v.z); o[3]=f2bf(v.w);
    *reinterpret_cast<short4_t*>(&As[r][c]) = o;
  }

  f32x4 acc[3][4];
  #pragma unroll
  for (int i=0;i<3;++i)
    #pragma unroll
    for (int j=0;j<4;++j) acc[i][j] = (f32x4)(0.f);

  const int fr = lane & 15;
  const int fk = (lane >> 4) * 8;
  const short* Wsrc = wallbf + ((size_t)s*G4 + tid)*FT_;

  for (int k0 = 0; k0 < FT_; k0 += 32) {
    // stage B: row n = tid, 32 shorts (64 B)
    {
      const short* src = Wsrc + k0;
      int4 w0 = *reinterpret_cast<const int4*>(src);
      int4 w1 = *reinterpret_cast<const int4*>(src + 8);
      int4 w2 = *reinterpret_cast<const int4*>(src + 16);
      int4 w3 = *reinterpret_cast<const int4*>(src + 24);
      *reinterpret_cast<int4*>(&Bs[tid][0])  = w0;
      *reinterpret_cast<int4*>(&Bs[tid][8])  = w1;
      *reinterpret_cast<int4*>(&Bs[tid][16]) = w2;
      *reinterpret_cast<int4*>(&Bs[tid][24]) = w3;
    }
    __syncthreads();
    short8_t a[3], b[4];
    #pragma unroll
    for (int i=0;i<3;++i)
      a[i] = *reinterpret_cast<const short8_t*>(&As[i*16 + fr][k0 + fk]);
    #pragma unroll
    for (int j=0;j<4;++j)
      b[j] = *reinterpret_cast<const short8_t*>(&Bs[wave*64 + j*16 + fr][fk]);
    #pragma unroll
    for (int i=0;i<3;++i)
      #pragma unroll
      for (int j=0;j<4;++j)
        acc[i][j] = __builtin_amdgcn_mfma_f32_16x16x32_bf16(a[i], b[j], acc[i][j], 0,0,0);
    __syncthreads();
  }

  // write GX to LDS (aliases As; all frag reads done)
  {
    const int cn = lane & 15;
    const int rm = (lane >> 4) * 4;
    #pragma unroll
    for (int j=0;j<4;++j) {
      const int n = wave*64 + j*16 + cn;
      const float bias = bW[s*G4+n] + bU[s*G4+n];
      #pragma unroll
      for (int i=0;i<3;++i) {
        #pragma unroll
        for (int r=0;r<4;++r) {
          const int m = i*16 + rm + r;
          if (m < T_) GXs[m][n] = acc[i][j][r] + bias;
        }
      }
    }
  }

  // ---------------- Phase 2: recurrence ----------------
  const int row = lane;  // = tid & 63
  const int q = wave;
  float u[64];
  {
    const float* Up = Uall + ((size_t)s*G4 + tid)*H_;
    #pragma unroll
    for (int j=0;j<64;++j) u[j] = Up[j];
  }
  float wd[16];
  {
    const float* Wp = Wd + ((size_t)s*H_ + row)*H_ + q*16;
    #pragma unroll
    for (int j=0;j<16;++j) wd[j] = Wp[j];
  }
  const float bdr = bd[s*H_ + row];
  if (tid < H_) { hs[tid]=0.f; cs[tid]=0.f; }
  __syncthreads();

  const float* tsp = ts + ((size_t)s*D_ + d)*T_;

  for (int t=0; t<T_; ++t) {
    float p = 0.f;
    #pragma unroll
    for (int j=0;j<16;++j) p = fmaf(wd[j], cs[q*16+j], p);
    pt[q][row] = p;

    float g = GXs[t][tid];
    const float4* h4 = reinterpret_cast<const float4*>(hs);
    #pragma unroll
    for (int j4=0;j4<16;++j4) {
      float4 hv = h4[j4];
      g = fmaf(u[j4*4+0], hv.x, g);
      g = fmaf(u[j4*4+1], hv.y, g);
      g = fmaf(u[j4*4+2], hv.z, g);
      g = fmaf(u[j4*4+3], hv.w, g);
    }
    gs[tid] = sigm(g);
    __syncthreads();
    if (tid < H_) {
      float cs1 = tanhf(pt[0][tid]+pt[1][tid]+pt[2][tid]+pt[3][tid] + bdr);
      float tv = tsp[t];
      float cadj = cs[tid] - cs1 + cs1*tv;
      float c2 = gs[tid]*cadj + gs[64+tid]*gs[192+tid];
      float h2 = gs[128+tid]*tanhf(c2);
      cs[tid] = c2; hs[tid] = h2; outs[t][tid] = h2;
    }
    __syncthreads();
  }

  // day attention
  {
    const float* Wp = taW + ((size_t)s*H_ + row)*H_ + q*16;
    float p = 0.f;
    #pragma unroll
    for (int j=0;j<16;++j) p = fmaf(Wp[j], hs[q*16+j], p);
    pt[q][row] = p;
    __syncthreads();
    if (tid < H_) vs[tid] = pt[0][tid]+pt[1][tid]+pt[2][tid]+pt[3][tid] + tab[s*H_+tid];
    __syncthreads();
    if (tid < T_) {
      float sc = 0.f;
      for (int h=0;h<H_;++h) sc = fmaf(outs[tid][h], vs[h], sc);
      as_[tid] = sc;
    }
    __syncthreads();
    if (tid == 0) {
      float m = -1e30f;
      for (int t=0;t<T_;++t) m = fmaxf(m, as_[t]);
      float sum = 0.f;
      for (int t=0;t<T_;++t) { float e = __expf(as_[t]-m); as_[t]=e; sum += e; }
      float inv = 1.0f/sum;
      for (int t=0;t<T_;++t) as_[t] *= inv;
    }
    __syncthreads();
    if (tid < H_) {
      float acc2 = 0.f;
      for (int t=0;t<T_;++t) acc2 = fmaf(as_[t], outs[t][tid], acc2);
      news[((size_t)s*D_ + d)*H_ + tid] = acc2;
    }
  }
}

// ---------------------------------------------------------------- K3: price GRU + attention -> xvec
__global__ __launch_bounds__(256) void k_price_gru(
    const float* __restrict__ price, const float* __restrict__ Wih,
    const float* __restrict__ Whh, const float* __restrict__ bih,
    const float* __restrict__ bhh, const float* __restrict__ paW,
    const float* __restrict__ pab, float* __restrict__ xvec)
{
  const int s = blockIdx.x;
  const int tid = threadIdx.x;
  const int row = tid & 63, q = tid >> 6;
  __shared__ float hs[H_];
  __shared__ float outs[D_][H_+1];
  __shared__ float gsum[128], gxn[64], ghn[64];
  __shared__ float pt[4][H_], vs[H_], as_[D_];

  float wih[3]; float whh[64]; float bihr=0.f, bhhr=0.f;
  if (tid < G3) {
    const float* wp = Wih + ((size_t)s*G3 + tid)*FP_;
    wih[0]=wp[0]; wih[1]=wp[1]; wih[2]=wp[2];
    const float* hp = Whh + ((size_t)s*G3 + tid)*H_;
    #pragma unroll
    for (int j=0;j<64;++j) whh[j]=hp[j];
    bihr = bih[s*G3+tid]; bhhr = bhh[s*G3+tid];
  }
  if (tid < H_) hs[tid]=0.f;
  __syncthreads();

  for (int d=0; d<D_; ++d) {
    const float* pp = price + ((size_t)s*D_ + d)*FP_;
    float p0=pp[0], p1=pp[1], p2=pp[2];
    if (tid < G3) {
      float gx = bihr + wih[0]*p0 + wih[1]*p1 + wih[2]*p2;
      float gh = bhhr;
      const float4* h4 = reinterpret_cast<const float4*>(hs);
      #pragma unroll
      for (int j4=0;j4<16;++j4) {
        float4 hv=h4[j4];
        gh = fmaf(whh[j4*4+0],hv.x,gh);
        gh = fmaf(whh[j4*4+1],hv.y,gh);
        gh = fmaf(whh[j4*4+2],hv.z,gh);
        gh = fmaf(whh[j4*4+3],hv.w,gh);
      }
      if (tid < 128) gsum[tid] = gx + gh;
      else { gxn[tid-128] = gx; ghn[tid-128] = gh; }
    }
    __syncthreads();
    if (tid < H_) {
      float r = sigm(gsum[tid]);
      float z = sigm(gsum[64+tid]);
      float n = tanhf(gxn[tid] + r*ghn[tid]);
      float h2 = (1.f-z)*n + z*hs[tid];
      hs[tid]=h2; outs[d][tid]=h2;
    }
    __syncthreads();
  }

  {
    const float* Wp = paW + ((size_t)s*H_ + row)*H_ + q*16;
    float p = 0.f;
    #pragma unroll
    for (int j=0;j<16;++j) p = fmaf(Wp[j], hs[q*16+j], p);
    pt[q][row] = p;
    __syncthreads();
    if (tid < H_) vs[tid] = pt[0][tid]+pt[1][tid]+pt[2][tid]+pt[3][tid] + pab[s*H_+tid];
    __syncthreads();
    if (tid < D_) {
      float sc = 0.f;
      for (int h=0;h<H_;++h) sc = fmaf(outs[tid][h], vs[h], sc);
      as_[tid] = sc;
    }
    __syncthreads();
    if (tid == 0) {
      float m = -1e30f;
      for (int t=0;t<D_;++t) m = fmaxf(m, as_[t]);
      float sum = 0.f;
      for (int t=0;t<D_;++t) { float e = __expf(as_[t]-m); as_[t]=e; sum += e; }
      float inv = 1.0f/sum;
      for (int t=0;t<D_;++t) as_[t] *= inv;
    }
    __syncthreads();
    if (tid < H_) {
      float acc = 0.f;
      for (int t=0;t<D_;++t) acc = fmaf(as_[t], outs[t][tid], acc);
      xvec[s*H_+tid] = acc;
    }
  }
}

// ---------------------------------------------------------------- K4: stock GRU over news + attention + bilinear -> feature
__global__ __launch_bounds__(256) void k_stock(
    const float* __restrict__ news, const float* __restrict__ Wih,
    const float* __restrict__ Whh, const float* __restrict__ bih,
    const float* __restrict__ bhh, const float* __restrict__ saW,
    const float* __restrict__ sab, const float* __restrict__ biW,
    const float* __restrict__ bib, const float* __restrict__ xvec,
    float* __restrict__ feat)
{
  const int s = blockIdx.x;
  const int tid = threadIdx.x;
  const int row = tid & 63, q = tid >> 6;
  __shared__ float xs[H_], hs[H_];
  __shared__ float outs[D_][H_+1];
  __shared__ float gsum[128], gxn[64], ghn[64];
  __shared__ float pt[4][H_], vs[H_], as_[D_];
  __shared__ float tv[H_], xv2[H_];
  __shared__ float pmat[H_*H_];

  float wih[64]; float whh[64]; float bihr=0.f, bhhr=0.f;
  if (tid < G3) {
    const float* wp = Wih + ((size_t)s*G3 + tid)*H_;
    const float* hp = Whh + ((size_t)s*G3 + tid)*H_;
    #pragma unroll
    for (int j=0;j<64;++j) { wih[j]=wp[j]; whh[j]=hp[j]; }
    bihr = bih[s*G3+tid]; bhhr = bhh[s*G3+tid];
  }
  if (tid < H_) hs[tid]=0.f;
  __syncthreads();

  for (int d=0; d<D_; ++d) {
    if (tid < H_) xs[tid] = news[((size_t)s*D_ + d)*H_ + tid];
    __syncthreads();
    if (tid < G3) {
      float gx = bihr, gh = bhhr;
      const float4* x4 = reinterpret_cast<const float4*>(xs);
      const float4* h4 = reinterpret_cast<const float4*>(hs);
      #pragma unroll
      for (int j4=0;j4<16;++j4) {
        float4 xv=x4[j4]; float4 hv=h4[j4];
        gx = fmaf(wih[j4*4+0],xv.x,gx); gx = fmaf(wih[j4*4+1],xv.y,gx);
        gx = fmaf(wih[j4*4+2],xv.z,gx); gx = fmaf(wih[j4*4+3],xv.w,gx);
        gh = fmaf(whh[j4*4+0],hv.x,gh); gh = fmaf(whh[j4*4+1],hv.y,gh);
        gh = fmaf(whh[j4*4+2],hv.z,gh); gh = fmaf(whh[j4*4+3],hv.w,gh);
      }
      if (tid < 128) gsum[tid] = gx + gh;
      else { gxn[tid-128] = gx; ghn[tid-128] = gh; }
    }
    __syncthreads();
    if (tid < H_) {
      float r = sigm(gsum[tid]);
      float z = sigm(gsum[64+tid]);
      float n = tanhf(gxn[tid] + r*ghn[tid]);
      float h2 = (1.f-z)*n + z*hs[tid];
      hs[tid]=h2; outs[d][tid]=h2;
    }
    __syncthreads();
  }

  // attention -> tvec
  {
    const float* Wp = saW + ((size_t)s*H_ + row)*H_ + q*16;
    float p = 0.f;
    #pragma unroll
    for (int j=0;j<16;++j) p = fmaf(Wp[j], hs[q*16+j], p);
    pt[q][row] = p;
    __syncthreads();
    if (tid < H_) vs[tid] = pt[0][tid]+pt[1][tid]+pt[2][tid]+pt[3][tid] + sab[s*H_+tid];
    __syncthreads();
    if (tid < D_) {
      float sc = 0.f;
      for (int h=0;h<H_;++h) sc = fmaf(outs[tid][h], vs[h], sc);
      as_[tid] = sc;
    }
    __syncthreads();
    if (tid == 0) {
      float m = -1e30f;
      for (int t=0;t<D_;++t) m = fmaxf(m, as_[t]);
      float sum = 0.f;
      for (int t=0;t<D_;++t) { float e = __expf(as_[t]-m); as_[t]=e; sum += e; }
      float inv = 1.0f/sum;
      for (int t=0;t<D_;++t) as_[t] *= inv;
    }
    __syncthreads();
    if (tid < H_) {
      float acc = 0.f;
      for (int t=0;t<D_;++t) acc = fmaf(as_[t], outs[t][tid], acc);
      tv[tid] = acc;
      xv2[tid] = xvec[s*H_+tid];
    }
    __syncthreads();
  }

  // bilinear: feat_k = tanh( sum_ij tv_i * biW[k,i,j] * xv_j + bib_k )
  for (int e=tid; e<H_*H_; e+=256) pmat[e] = tv[e>>6]*xv2[e&63];
  __syncthreads();
  {
    const float* Wk0 = biW + (size_t)s*H_*H_*H_;
    const int lane = tid & 63, w = tid >> 6;
    const float4* P4 = reinterpret_cast<const float4*>(pmat);
    for (int k = w; k < H_; k += 4) {
      const float4* W4 = reinterpret_cast<const float4*>(Wk0 + (size_t)k*H_*H_);
      float acc = 0.f;
      #pragma unroll 4
      for (int r=0;r<16;++r) {
        float4 wv = W4[r*64+lane];
        float4 pv = P4[r*64+lane];
        acc += wv.x*pv.x + wv.y*pv.y + wv.z*pv.z + wv.w*pv.w;
      }
      #pragma unroll
      for (int off=32; off>0; off>>=1) acc += __shfl_down(acc, off, 64);
      if (lane==0) feat[s*H_+k] = tanhf(acc + bib[s*H_+k]);
    }
  }
}

// ---------------------------------------------------------------- K5: head (out_1, MHA, elu, softmax, loss)
__global__ __launch_bounds__(1024) void k_head(
    const float* __restrict__ feat, const float* __restrict__ blW,
    const float* __restrict__ blb, const float* __restrict__ Wq,
    const float* __restrict__ bq, const float* __restrict__ Wk,
    const float* __restrict__ bk, const float* __restrict__ fcW,
    const float* __restrict__ fcb, const int* __restrict__ label,
    float* __restrict__ Qg, float* __restrict__ Kg, float* __restrict__ scw,
    float* __restrict__ dout)
{
  const int tid = threadIdx.x;
  __shared__ float fs[S_*H_];
  __shared__ float mhs[S_*H_];
  __shared__ float o1[S_*2];
  __shared__ float lt[S_];

  for (int e=tid; e<S_*H_; e+=1024) fs[e] = feat[e];
  __syncthreads();

  if (tid < 2*S_) {
    int s = tid>>1, c = tid&1;
    const float* w = blW + ((size_t)(S_-1)*2 + c)*H_;
    float a = blb[(S_-1)*2 + c];
    for (int h=0;h<H_;++h) a = fmaf(fs[s*H_+h], w[h], a);
    o1[tid] = tanhf(a);
  }
  for (int e=tid; e<S_*H_; e+=1024) {
    int s = e>>6, o = e&63;
    float aq = bq[o], ak = bk[o];
    const float* wq = Wq + o*H_;
    const float* wk = Wk + o*H_;
    for (int h=0;h<H_;++h) { float f = fs[s*H_+h]; aq = fmaf(f, wq[h], aq); ak = fmaf(f, wk[h], ak); }
    Qg[e]=aq; Kg[e]=ak;
  }
  __syncthreads();

  if (tid < 4*S_) {
    int s = tid % S_, hd = tid / S_;
    const float* qr = Qg + s*H_ + hd*16;
    float m = -1e30f;
    for (int t=0;t<S_;++t) {
      const float* kr = Kg + t*H_ + hd*16;
      float sc=0.f;
      #pragma unroll
      for (int d2=0; d2<16; ++d2) sc = fmaf(qr[d2], kr[d2], sc);
      sc *= 0.25f;
      scw[(size_t)tid*S_+t]=sc;
      m = fmaxf(m, sc);
    }
    float sum=0.f;
    for (int t=0;t<S_;++t) { float e=__expf(scw[(size_t)tid*S_+t]-m); scw[(size_t)tid*S_+t]=e; sum+=e; }
    float inv=1.f/sum;
    float acc[16];
    #pragma unroll
    for (int d2=0;d2<16;++d2) acc[d2]=0.f;
    for (int t=0;t<S_;++t) {
      float a = scw[(size_t)tid*S_+t]*inv;
      #pragma unroll
      for (int d2=0;d2<16;++d2) acc[d2] = fmaf(a, fs[t*H_ + hd*16 + d2], acc[d2]);
    }
    #pragma unroll
    for (int d2=0;d2<16;++d2) mhs[s*H_ + hd*16 + d2] = acc[d2];
  }
  __syncthreads();

  if (tid < S_) {
    int s = tid;
    float e0 = fcb[0], e1 = fcb[1];
    for (int h=0;h<H_;++h) { float mv = mhs[s*H_+h]; e0 = fmaf(mv, fcW[h], e0); e1 = fmaf(mv, fcW[H_+h], e1); }
    float x0 = e0>0.f?e0:(__expf(e0)-1.f);
    float x1 = e1>0.f?e1:(__expf(e1)-1.f);
    float y0 = x0 + o1[s*2], y1 = x1 + o1[s*2+1];
    float mm = fmaxf(y0,y1);
    float p0 = __expf(y0-mm), p1=__expf(y1-mm);
    float is = 1.f/(p0+p1);
    float out0 = p0*is, out1 = p1*is;
    float m2 = fmaxf(out0,out1);
    float lse = m2 + logf(__expf(out0-m2)+__expf(out1-m2));
    float ol = (label[s]!=0) ? out1 : out0;
    lt[s] = lse - ol;
    dout[1 + s*2]   = out0;
    dout[2 + s*2]   = out1;
  }
  __syncthreads();
  if (tid==0) {
    float sum=0.f;
    for (int s=0;s<S_;++s) sum += lt[s];
    dout[0] = sum * (1.0f/(float)S_);
  }
}

// ---------------------------------------------------------------- launch
extern "C" void kernel_launch(void* const* d_in, const int* in_sizes, int n_in,
                              void* d_out, int out_size, void* d_ws, size_t ws_size,
                              hipStream_t stream) {
  const float* pg_Wih  = (const float*)d_in[0];
  const float* pg_Whh  = (const float*)d_in[1];
  const float* pg_bih  = (const float*)d_in[2];
  const float* pg_bhh  = (const float*)d_in[3];
  const float* pa_W    = (const float*)d_in[4];
  const float* pa_b    = (const float*)d_in[5];
  const float* tl_Wall = (const float*)d_in[6];
  const float* tl_bWall= (const float*)d_in[7];
  const float* tl_Uall = (const float*)d_in[8];
  const float* tl_bUall= (const float*)d_in[9];
  const float* tl_Wd   = (const float*)d_in[10];
  const float* tl_bd   = (const float*)d_in[11];
  const float* ta_W    = (const float*)d_in[12];
  const float* ta_b    = (const float*)d_in[13];
  const float* sg_Wih  = (const float*)d_in[14];
  const float* sg_Whh  = (const float*)d_in[15];
  const float* sg_bih  = (const float*)d_in[16];
  const float* sg_bhh  = (const float*)d_in[17];
  const float* sa_W    = (const float*)d_in[18];
  const float* sa_b    = (const float*)d_in[19];
  const float* bi_W    = (const float*)d_in[20];
  const float* bi_b    = (const float*)d_in[21];
  const float* bl_W    = (const float*)d_in[22];
  const float* bl_b    = (const float*)d_in[23];
  const float* mha_Wq  = (const float*)d_in[24];
  const float* mha_bq  = (const float*)d_in[25];
  const float* mha_Wk  = (const float*)d_in[26];
  const float* mha_bk  = (const float*)d_in[27];
  const float* fc_W    = (const float*)d_in[28];
  const float* fc_b    = (const float*)d_in[29];
  const float* text    = (const float*)d_in[30];
  const float* price   = (const float*)d_in[31];
  const float* tstamps = (const float*)d_in[32];
  const int*   label   = (const int*)d_in[33];
  (void)in_sizes; (void)n_in; (void)out_size; (void)ws_size;

  // ws layout
  short* wallbf = (short*)d_ws;                         // 13,107,200 shorts = 26,214,400 B
  float* fws  = (float*)((char*)d_ws + (size_t)S_*G4*FT_*sizeof(short));
  float* news = fws;                                    // 192,000
  float* xvec = news + (size_t)S_*D_*H_;                // 6,400
  float* feat = xvec + (size_t)S_*H_;                   // 6,400
  float* Qg   = feat + (size_t)S_*H_;                   // 6,400
  float* Kg   = Qg   + (size_t)S_*H_;                   // 6,400
  float* scw  = Kg   + (size_t)S_*H_;                   // 40,000
  float* dout = (float*)d_out;

  k_conv_wall<<<2048, 256, 0, stream>>>(tl_Wall, wallbf);
  k_fused_text<<<S_*D_, 256, 0, stream>>>(text, wallbf, tl_bWall, tl_bUall,
                                          tl_Uall, tl_Wd, tl_bd, ta_W, ta_b, tstamps, news);
  k_price_gru<<<S_, 256, 0, stream>>>(price, pg_Wih, pg_Whh, pg_bih, pg_bhh, pa_W, pa_b, xvec);
  k_stock<<<S_, 256, 0, stream>>>(news, sg_Wih, sg_Whh, sg_bih, sg_bhh, sa_W, sa_b, bi_W, bi_b, xvec, feat);
  k_head<<<1, 1024, 0, stream>>>(feat, bl_W, bl_b, mha_Wq, mha_bq, mha_Wk, mha_bk, fc_W, fc_b, label, Qg, Kg, scw, dout);
}

// Round 4
// 558.338 us; speedup vs baseline: 1.5557x; 1.0662x over previous
//
#include <hip/hip_runtime.h>
#include <math.h>

#define S_  100
#define D_  30
#define T_  40
#define FT_ 512
#define FP_ 3
#define H_  64
#define G3  192
#define G4  256
#define M_  (D_*T_)   // 1200

typedef __attribute__((ext_vector_type(8))) short short8_t;
typedef __attribute__((ext_vector_type(4))) short short4_t;
typedef __attribute__((ext_vector_type(4))) float f32x4;

__device__ __forceinline__ float sigm(float x){ return 1.0f/(1.0f+__expf(-x)); }
__device__ __forceinline__ float tanhfast(float x){
  float e = __expf(2.0f*x);
  return 1.0f - 2.0f/(e + 1.0f);
}
__device__ __forceinline__ short f2bf(float f){
  unsigned u = __builtin_bit_cast(unsigned, f);
  u += 0x7FFFu + ((u>>16)&1u);
  return (short)(u>>16);
}
__device__ __forceinline__ float bf2f(unsigned short u){
  unsigned x = ((unsigned)u) << 16;
  return __builtin_bit_cast(float, x);
}

// ---------------------------------------------------------------- K0: convert params (Wall/Uall/Wd -> bf16, taW -> transposed f32)
__global__ __launch_bounds__(256) void k_conv(
    const float* __restrict__ Wall, const float* __restrict__ Uall,
    const float* __restrict__ Wd, const float* __restrict__ taW,
    short* __restrict__ WallBf, short* __restrict__ Ubf,
    short* __restrict__ Wdbf, float* __restrict__ taWT)
{
  const int tid = blockIdx.x*256 + threadIdx.x;
  const int stride = gridDim.x*256;
  for (int i = tid; i < (S_*G4*FT_)/4; i += stride) {
    float4 v = reinterpret_cast<const float4*>(Wall)[i];
    short4_t o; o[0]=f2bf(v.x); o[1]=f2bf(v.y); o[2]=f2bf(v.z); o[3]=f2bf(v.w);
    reinterpret_cast<short4_t*>(WallBf)[i] = o;
  }
  for (int i = tid; i < (S_*G4*H_)/4; i += stride) {
    float4 v = reinterpret_cast<const float4*>(Uall)[i];
    short4_t o; o[0]=f2bf(v.x); o[1]=f2bf(v.y); o[2]=f2bf(v.z); o[3]=f2bf(v.w);
    reinterpret_cast<short4_t*>(Ubf)[i] = o;
  }
  for (int i = tid; i < (S_*H_*H_)/4; i += stride) {
    float4 v = reinterpret_cast<const float4*>(Wd)[i];
    short4_t o; o[0]=f2bf(v.x); o[1]=f2bf(v.y); o[2]=f2bf(v.z); o[3]=f2bf(v.w);
    reinterpret_cast<short4_t*>(Wdbf)[i] = o;
  }
  for (int i = tid; i < S_*H_*H_; i += stride) {
    int s = i >> 12, j = (i >> 6) & 63, c = i & 63;
    taWT[i] = taW[(s << 12) + (c << 6) + j];
  }
}

// ---------------------------------------------------------------- K1: GX[s][t][d][gate] (bf16) = text @ Wall^T + bW + bU
#define LDT 72
__global__ __launch_bounds__(256) void k_gemm(
    const float* __restrict__ text, const short* __restrict__ WallBf,
    const float* __restrict__ bW, const float* __restrict__ bU,
    unsigned short* __restrict__ GX)
{
  const int bid = blockIdx.x;
  const int s  = bid / 19;
  const int mb = bid % 19;
  const int m0 = mb * 64;
  const int tid = threadIdx.x;
  const int lane = tid & 63, wave = tid >> 6;
  const int fr = lane & 15, fk = (lane >> 4) * 8;

  __shared__ short As[64][LDT];
  __shared__ short Bs[256][LDT];

  const float* X  = text + (size_t)s * ((size_t)M_*FT_);
  const short* Wb = WallBf + (size_t)s * ((size_t)G4*FT_);

  f32x4 acc[4][4];
  #pragma unroll
  for (int i=0;i<4;++i)
    #pragma unroll
    for (int j=0;j<4;++j) acc[i][j] = (f32x4)(0.f);

  for (int kp = 0; kp < 8; ++kp) {
    const int k0 = kp * 64;
    // stage A: 64x64 fp32 -> bf16
    #pragma unroll
    for (int j = 0; j < 4; ++j) {
      int idx = tid + 256*j;
      int r = idx >> 4;
      int c4 = (idx & 15) * 4;
      int m = m0 + r;
      short4_t o;
      if (m < M_) {
        float4 v = *reinterpret_cast<const float4*>(X + (size_t)m*FT_ + k0 + c4);
        o[0]=f2bf(v.x); o[1]=f2bf(v.y); o[2]=f2bf(v.z); o[3]=f2bf(v.w);
      } else {
        o = (short4_t)(short)0;
      }
      *reinterpret_cast<short4_t*>(&As[r][c4]) = o;
    }
    // stage B: 256x64 bf16 copy
    #pragma unroll
    for (int j = 0; j < 8; ++j) {
      int idx = tid + 256*j;
      int row = idx >> 3, q = idx & 7;
      *reinterpret_cast<int4*>(&Bs[row][q*8]) =
          *reinterpret_cast<const int4*>(Wb + (size_t)row*FT_ + k0 + q*8);
    }
    __syncthreads();
    #pragma unroll
    for (int kw = 0; kw < 2; ++kw) {
      short8_t a[4], b[4];
      #pragma unroll
      for (int mt=0; mt<4; ++mt)
        a[mt] = *reinterpret_cast<const short8_t*>(&As[mt*16 + fr][kw*32 + fk]);
      #pragma unroll
      for (int nt=0; nt<4; ++nt)
        b[nt] = *reinterpret_cast<const short8_t*>(&Bs[wave*64 + nt*16 + fr][kw*32 + fk]);
      #pragma unroll
      for (int mt=0; mt<4; ++mt)
        #pragma unroll
        for (int nt=0; nt<4; ++nt)
          acc[mt][nt] = __builtin_amdgcn_mfma_f32_16x16x32_bf16(a[mt], b[nt], acc[mt][nt], 0,0,0);
    }
    __syncthreads();
  }

  const int l15 = lane & 15, h4 = (lane >> 4) * 4;
  #pragma unroll
  for (int nt = 0; nt < 4; ++nt) {
    const int n = wave*64 + nt*16 + l15;
    const float bias = bW[s*G4 + n] + bU[s*G4 + n];
    #pragma unroll
    for (int mt = 0; mt < 4; ++mt) {
      #pragma unroll
      for (int r = 0; r < 4; ++r) {
        const int m = m0 + mt*16 + h4 + r;
        if (m < M_) {
          const int d = m / T_, t = m % T_;
          GX[(((size_t)s*T_ + t)*D_ + d)*G4 + n] = (unsigned short)f2bf(acc[mt][nt][r] + bias);
        }
      }
    }
  }
}

// ---------------------------------------------------------------- K2: batched TimeLSTM per stock (MFMA over 30 days) -> outs
__global__ __launch_bounds__(256, 2) void k_recur(
    const unsigned short* __restrict__ GX, const short* __restrict__ Ubf,
    const short* __restrict__ Wdbf, const float* __restrict__ bd,
    const float* __restrict__ ts, float* __restrict__ outs)
{
  const int s = blockIdx.x;
  const int tid = threadIdx.x;
  const int lane = tid & 63, wave = tid >> 6;
  const int fr = lane & 15, fk = (lane >> 4) * 8;
  const int l15 = lane & 15, h4 = (lane >> 4) * 4;
  const int mhalf = wave >> 1, nt = wave & 1;

  __shared__ float G1[32][260];   // [day][gate], padded
  __shared__ float G2l[32][68];   // [day][i]
  __shared__ float Cf[32][68];    // cell state fp32 [day][i]
  __shared__ short Hn[32][72];    // h bf16 [day][i]
  __shared__ short Cn[32][72];    // c bf16 [day][i]
  __shared__ float tsl[D_][T_];
  __shared__ float bdl[H_];

  for (int e = tid; e < 32*72; e += 256) { (&Hn[0][0])[e] = 0; (&Cn[0][0])[e] = 0; }
  for (int e = tid; e < 32*68; e += 256) (&Cf[0][0])[e] = 0.f;
  for (int e = tid; e < D_*T_; e += 256) tsl[e / T_][e % T_] = ts[(size_t)s*D_*T_ + e];
  if (tid < H_) bdl[tid] = bd[s*H_ + tid];
  __syncthreads();

  const short* Ub  = Ubf  + (size_t)s*G4*H_;
  const short* Wdb = Wdbf + (size_t)s*H_*H_;

  for (int t = 0; t < T_; ++t) {
    // prefetch this step's GX slab (consumed after the barrier)
    const unsigned short* GXt = GX + ((size_t)(s*T_ + t)*D_)*G4;
    float gx0[8], gx1[8], gx2[8], gx3[8];
    #pragma unroll
    for (int it = 0; it < 8; ++it) {
      int d = it*4 + wave;
      if (d < D_) {
        const unsigned short* p = GXt + d*G4 + lane;
        gx0[it] = bf2f(p[0]);
        gx1[it] = bf2f(p[64]);
        gx2[it] = bf2f(p[128]);
        gx3[it] = bf2f(p[192]);
      }
    }

    // MFMA: G1 = U @ H (256x30), G2 = Wd @ C (64x30)
    f32x4 acc1[8], acc2[2];
    #pragma unroll
    for (int mt=0; mt<8; ++mt) acc1[mt] = (f32x4)(0.f);
    acc2[0] = (f32x4)(0.f); acc2[1] = (f32x4)(0.f);

    #pragma unroll
    for (int kw = 0; kw < 2; ++kw) {
      short8_t bfrag = *reinterpret_cast<const short8_t*>(&Hn[nt*16 + fr][kw*32 + fk]);
      #pragma unroll
      for (int mt = 0; mt < 8; ++mt) {
        short8_t afrag = *reinterpret_cast<const short8_t*>(
            Ub + (size_t)(mhalf*128 + mt*16 + fr)*H_ + kw*32 + fk);
        acc1[mt] = __builtin_amdgcn_mfma_f32_16x16x32_bf16(afrag, bfrag, acc1[mt], 0,0,0);
      }
      short8_t a2 = *reinterpret_cast<const short8_t*>(
          Wdb + (size_t)(wave*16 + fr)*H_ + kw*32 + fk);
      #pragma unroll
      for (int n2 = 0; n2 < 2; ++n2) {
        short8_t b2 = *reinterpret_cast<const short8_t*>(&Cn[n2*16 + fr][kw*32 + fk]);
        acc2[n2] = __builtin_amdgcn_mfma_f32_16x16x32_bf16(a2, b2, acc2[n2], 0,0,0);
      }
    }
    #pragma unroll
    for (int mt = 0; mt < 8; ++mt)
      *reinterpret_cast<f32x4*>(&G1[nt*16 + l15][mhalf*128 + mt*16 + h4]) = acc1[mt];
    #pragma unroll
    for (int n2 = 0; n2 < 2; ++n2)
      *reinterpret_cast<f32x4*>(&G2l[n2*16 + l15][wave*16 + h4]) = acc2[n2];
    __syncthreads();

    // elementwise update (gates f,i,o,ct all sigmoid per reference)
    float* outp = outs + ((size_t)(s*T_ + t)*D_)*H_;
    #pragma unroll
    for (int it = 0; it < 8; ++it) {
      int d = it*4 + wave;
      if (d < D_) {
        float gf = G1[d][lane]        + gx0[it];
        float gi = G1[d][64 + lane]   + gx1[it];
        float go = G1[d][128 + lane]  + gx2[it];
        float gc = G1[d][192 + lane]  + gx3[it];
        float f  = sigm(gf), ig = sigm(gi), og = sigm(go), ct = sigm(gc);
        float cs1 = tanhfast(G2l[d][lane] + bdl[lane]);
        float tv = tsl[d][t];
        float c  = Cf[d][lane];
        float cadj = c - cs1 + cs1*tv;
        float c2 = f*cadj + ig*ct;
        float h2 = og*tanhfast(c2);
        Cf[d][lane] = c2;
        Cn[d][lane] = f2bf(c2);
        Hn[d][lane] = f2bf(h2);
        outp[d*H_ + lane] = h2;
      }
    }
    __syncthreads();
  }
}

// ---------------------------------------------------------------- K3: day attention -> news
__global__ __launch_bounds__(64) void k_dayattn(
    const float* __restrict__ outs, const float* __restrict__ taWT,
    const float* __restrict__ tab, float* __restrict__ news)
{
  const int blk = blockIdx.x;
  const int s = blk / D_, d = blk % D_;
  const int lane = threadIdx.x;
  __shared__ float ol[T_][68];
  __shared__ float vv[H_];
  __shared__ float aw[64];

  #pragma unroll 4
  for (int t = 0; t < T_; ++t)
    ol[t][lane] = outs[((size_t)(s*T_ + t)*D_ + d)*H_ + lane];
  __syncthreads();

  float acc = tab[s*H_ + lane];
  const float* Wp = taWT + (size_t)s*H_*H_;
  #pragma unroll 8
  for (int j = 0; j < H_; ++j)
    acc = fmaf(Wp[j*H_ + lane], ol[T_-1][j], acc);
  vv[lane] = acc;
  __syncthreads();

  float sc = -1e30f;
  if (lane < T_) {
    sc = 0.f;
    for (int h = 0; h < H_; ++h) sc = fmaf(ol[lane][h], vv[h], sc);
  }
  float m = sc;
  #pragma unroll
  for (int off = 32; off > 0; off >>= 1) m = fmaxf(m, __shfl_xor(m, off, 64));
  float e = (lane < T_) ? __expf(sc - m) : 0.f;
  float sum = e;
  #pragma unroll
  for (int off = 32; off > 0; off >>= 1) sum += __shfl_xor(sum, off, 64);
  aw[lane] = e / sum;
  __syncthreads();

  float o = 0.f;
  #pragma unroll 8
  for (int t = 0; t < T_; ++t) o = fmaf(aw[t], ol[t][lane], o);
  news[((size_t)s*D_ + d)*H_ + lane] = o;
}

// ---------------------------------------------------------------- K4: price GRU + attention -> xvec
__global__ __launch_bounds__(256) void k_price_gru(
    const float* __restrict__ price, const float* __restrict__ Wih,
    const float* __restrict__ Whh, const float* __restrict__ bih,
    const float* __restrict__ bhh, const float* __restrict__ paW,
    const float* __restrict__ pab, float* __restrict__ xvec)
{
  const int s = blockIdx.x;
  const int tid = threadIdx.x;
  const int row = tid & 63, q = tid >> 6;
  __shared__ float hs[H_];
  __shared__ float outsb[D_][H_+1];
  __shared__ float gsum[128], gxn[64], ghn[64];
  __shared__ float pt[4][H_], vs[H_], as_[D_];

  float wih[3]; float whh[64]; float bihr=0.f, bhhr=0.f;
  if (tid < G3) {
    const float* wp = Wih + ((size_t)s*G3 + tid)*FP_;
    wih[0]=wp[0]; wih[1]=wp[1]; wih[2]=wp[2];
    const float* hp = Whh + ((size_t)s*G3 + tid)*H_;
    #pragma unroll
    for (int j=0;j<64;++j) whh[j]=hp[j];
    bihr = bih[s*G3+tid]; bhhr = bhh[s*G3+tid];
  }
  if (tid < H_) hs[tid]=0.f;
  __syncthreads();

  for (int d=0; d<D_; ++d) {
    const float* pp = price + ((size_t)s*D_ + d)*FP_;
    float p0=pp[0], p1=pp[1], p2=pp[2];
    if (tid < G3) {
      float gx = bihr + wih[0]*p0 + wih[1]*p1 + wih[2]*p2;
      float gh = bhhr;
      const float4* h4p = reinterpret_cast<const float4*>(hs);
      #pragma unroll
      for (int j4=0;j4<16;++j4) {
        float4 hv=h4p[j4];
        gh = fmaf(whh[j4*4+0],hv.x,gh);
        gh = fmaf(whh[j4*4+1],hv.y,gh);
        gh = fmaf(whh[j4*4+2],hv.z,gh);
        gh = fmaf(whh[j4*4+3],hv.w,gh);
      }
      if (tid < 128) gsum[tid] = gx + gh;
      else { gxn[tid-128] = gx; ghn[tid-128] = gh; }
    }
    __syncthreads();
    if (tid < H_) {
      float r = sigm(gsum[tid]);
      float z = sigm(gsum[64+tid]);
      float n = tanhf(gxn[tid] + r*ghn[tid]);
      float h2 = (1.f-z)*n + z*hs[tid];
      hs[tid]=h2; outsb[d][tid]=h2;
    }
    __syncthreads();
  }

  {
    const float* Wp = paW + ((size_t)s*H_ + row)*H_ + q*16;
    float p = 0.f;
    #pragma unroll
    for (int j=0;j<16;++j) p = fmaf(Wp[j], hs[q*16+j], p);
    pt[q][row] = p;
    __syncthreads();
    if (tid < H_) vs[tid] = pt[0][tid]+pt[1][tid]+pt[2][tid]+pt[3][tid] + pab[s*H_+tid];
    __syncthreads();
    if (tid < D_) {
      float sc = 0.f;
      for (int h=0;h<H_;++h) sc = fmaf(outsb[tid][h], vs[h], sc);
      as_[tid] = sc;
    }
    __syncthreads();
    if (tid == 0) {
      float m = -1e30f;
      for (int t=0;t<D_;++t) m = fmaxf(m, as_[t]);
      float sum = 0.f;
      for (int t=0;t<D_;++t) { float e = __expf(as_[t]-m); as_[t]=e; sum += e; }
      float inv = 1.0f/sum;
      for (int t=0;t<D_;++t) as_[t] *= inv;
    }
    __syncthreads();
    if (tid < H_) {
      float acc = 0.f;
      for (int t=0;t<D_;++t) acc = fmaf(as_[t], outsb[t][tid], acc);
      xvec[s*H_+tid] = acc;
    }
  }
}

// ---------------------------------------------------------------- K5: stock GRU over news + attention + bilinear -> feature
__global__ __launch_bounds__(256) void k_stock(
    const float* __restrict__ news, const float* __restrict__ Wih,
    const float* __restrict__ Whh, const float* __restrict__ bih,
    const float* __restrict__ bhh, const float* __restrict__ saW,
    const float* __restrict__ sab, const float* __restrict__ biW,
    const float* __restrict__ bib, const float* __restrict__ xvec,
    float* __restrict__ feat)
{
  const int s = blockIdx.x;
  const int tid = threadIdx.x;
  const int row = tid & 63, q = tid >> 6;
  __shared__ float xs[H_], hs[H_];
  __shared__ float outsb[D_][H_+1];
  __shared__ float gsum[128], gxn[64], ghn[64];
  __shared__ float pt[4][H_], vs[H_], as_[D_];
  __shared__ float tv[H_], xv2[H_];
  __shared__ float pmat[H_*H_];

  float wih[64]; float whh[64]; float bihr=0.f, bhhr=0.f;
  if (tid < G3) {
    const float* wp = Wih + ((size_t)s*G3 + tid)*H_;
    const float* hp = Whh + ((size_t)s*G3 + tid)*H_;
    #pragma unroll
    for (int j=0;j<64;++j) { wih[j]=wp[j]; whh[j]=hp[j]; }
    bihr = bih[s*G3+tid]; bhhr = bhh[s*G3+tid];
  }
  if (tid < H_) hs[tid]=0.f;
  __syncthreads();

  for (int d=0; d<D_; ++d) {
    if (tid < H_) xs[tid] = news[((size_t)s*D_ + d)*H_ + tid];
    __syncthreads();
    if (tid < G3) {
      float gx = bihr, gh = bhhr;
      const float4* x4 = reinterpret_cast<const float4*>(xs);
      const float4* h4p = reinterpret_cast<const float4*>(hs);
      #pragma unroll
      for (int j4=0;j4<16;++j4) {
        float4 xv=x4[j4]; float4 hv=h4p[j4];
        gx = fmaf(wih[j4*4+0],xv.x,gx); gx = fmaf(wih[j4*4+1],xv.y,gx);
        gx = fmaf(wih[j4*4+2],xv.z,gx); gx = fmaf(wih[j4*4+3],xv.w,gx);
        gh = fmaf(whh[j4*4+0],hv.x,gh); gh = fmaf(whh[j4*4+1],hv.y,gh);
        gh = fmaf(whh[j4*4+2],hv.z,gh); gh = fmaf(whh[j4*4+3],hv.w,gh);
      }
      if (tid < 128) gsum[tid] = gx + gh;
      else { gxn[tid-128] = gx; ghn[tid-128] = gh; }
    }
    __syncthreads();
    if (tid < H_) {
      float r = sigm(gsum[tid]);
      float z = sigm(gsum[64+tid]);
      float n = tanhf(gxn[tid] + r*ghn[tid]);
      float h2 = (1.f-z)*n + z*hs[tid];
      hs[tid]=h2; outsb[d][tid]=h2;
    }
    __syncthreads();
  }

  {
    const float* Wp = saW + ((size_t)s*H_ + row)*H_ + q*16;
    float p = 0.f;
    #pragma unroll
    for (int j=0;j<16;++j) p = fmaf(Wp[j], hs[q*16+j], p);
    pt[q][row] = p;
    __syncthreads();
    if (tid < H_) vs[tid] = pt[0][tid]+pt[1][tid]+pt[2][tid]+pt[3][tid] + sab[s*H_+tid];
    __syncthreads();
    if (tid < D_) {
      float sc = 0.f;
      for (int h=0;h<H_;++h) sc = fmaf(outsb[tid][h], vs[h], sc);
      as_[tid] = sc;
    }
    __syncthreads();
    if (tid == 0) {
      float m = -1e30f;
      for (int t=0;t<D_;++t) m = fmaxf(m, as_[t]);
      float sum = 0.f;
      for (int t=0;t<D_;++t) { float e = __expf(as_[t]-m); as_[t]=e; sum += e; }
      float inv = 1.0f/sum;
      for (int t=0;t<D_;++t) as_[t] *= inv;
    }
    __syncthreads();
    if (tid < H_) {
      float acc = 0.f;
      for (int t=0;t<D_;++t) acc = fmaf(as_[t], outsb[t][tid], acc);
      tv[tid] = acc;
      xv2[tid] = xvec[s*H_+tid];
    }
    __syncthreads();
  }

  for (int e=tid; e<H_*H_; e+=256) pmat[e] = tv[e>>6]*xv2[e&63];
  __syncthreads();
  {
    const float* Wk0 = biW + (size_t)s*H_*H_*H_;
    const int lane = tid & 63, w = tid >> 6;
    const float4* P4 = reinterpret_cast<const float4*>(pmat);
    for (int k = w; k < H_; k += 4) {
      const float4* W4 = reinterpret_cast<const float4*>(Wk0 + (size_t)k*H_*H_);
      float acc = 0.f;
      #pragma unroll 4
      for (int r=0;r<16;++r) {
        float4 wv = W4[r*64+lane];
        float4 pv = P4[r*64+lane];
        acc += wv.x*pv.x + wv.y*pv.y + wv.z*pv.z + wv.w*pv.w;
      }
      #pragma unroll
      for (int off=32; off>0; off>>=1) acc += __shfl_down(acc, off, 64);
      if (lane==0) feat[s*H_+k] = tanhf(acc + bib[s*H_+k]);
    }
  }
}

// ---------------------------------------------------------------- K6: head
__global__ __launch_bounds__(1024) void k_head(
    const float* __restrict__ feat, const float* __restrict__ blW,
    const float* __restrict__ blb, const float* __restrict__ Wq,
    const float* __restrict__ bq, const float* __restrict__ Wk,
    const float* __restrict__ bk, const float* __restrict__ fcW,
    const float* __restrict__ fcb, const int* __restrict__ label,
    float* __restrict__ Qg, float* __restrict__ Kg, float* __restrict__ scw,
    float* __restrict__ dout)
{
  const int tid = threadIdx.x;
  __shared__ float fs[S_*H_];
  __shared__ float mhs[S_*H_];
  __shared__ float o1[S_*2];
  __shared__ float lt[S_];

  for (int e=tid; e<S_*H_; e+=1024) fs[e] = feat[e];
  __syncthreads();

  if (tid < 2*S_) {
    int s = tid>>1, c = tid&1;
    const float* w = blW + ((size_t)(S_-1)*2 + c)*H_;
    float a = blb[(S_-1)*2 + c];
    for (int h=0;h<H_;++h) a = fmaf(fs[s*H_+h], w[h], a);
    o1[tid] = tanhf(a);
  }
  for (int e=tid; e<S_*H_; e+=1024) {
    int s = e>>6, o = e&63;
    float aq = bq[o], ak = bk[o];
    const float* wq = Wq + o*H_;
    const float* wk = Wk + o*H_;
    for (int h=0;h<H_;++h) { float f = fs[s*H_+h]; aq = fmaf(f, wq[h], aq); ak = fmaf(f, wk[h], ak); }
    Qg[e]=aq; Kg[e]=ak;
  }
  __syncthreads();

  if (tid < 4*S_) {
    int s = tid % S_, hd = tid / S_;
    const float* qr = Qg + s*H_ + hd*16;
    float m = -1e30f;
    for (int t=0;t<S_;++t) {
      const float* kr = Kg + t*H_ + hd*16;
      float sc=0.f;
      #pragma unroll
      for (int d2=0; d2<16; ++d2) sc = fmaf(qr[d2], kr[d2], sc);
      sc *= 0.25f;
      scw[(size_t)tid*S_+t]=sc;
      m = fmaxf(m, sc);
    }
    float sum=0.f;
    for (int t=0;t<S_;++t) { float e=__expf(scw[(size_t)tid*S_+t]-m); scw[(size_t)tid*S_+t]=e; sum+=e; }
    float inv=1.f/sum;
    float acc[16];
    #pragma unroll
    for (int d2=0;d2<16;++d2) acc[d2]=0.f;
    for (int t=0;t<S_;++t) {
      float a = scw[(size_t)tid*S_+t]*inv;
      #pragma unroll
      for (int d2=0;d2<16;++d2) acc[d2] = fmaf(a, fs[t*H_ + hd*16 + d2], acc[d2]);
    }
    #pragma unroll
    for (int d2=0;d2<16;++d2) mhs[s*H_ + hd*16 + d2] = acc[d2];
  }
  __syncthreads();

  if (tid < S_) {
    int s = tid;
    float e0 = fcb[0], e1 = fcb[1];
    for (int h=0;h<H_;++h) { float mv = mhs[s*H_+h]; e0 = fmaf(mv, fcW[h], e0); e1 = fmaf(mv, fcW[H_+h], e1); }
    float x0 = e0>0.f?e0:(__expf(e0)-1.f);
    float x1 = e1>0.f?e1:(__expf(e1)-1.f);
    float y0 = x0 + o1[s*2], y1 = x1 + o1[s*2+1];
    float mm = fmaxf(y0,y1);
    float p0 = __expf(y0-mm), p1=__expf(y1-mm);
    float is = 1.f/(p0+p1);
    float out0 = p0*is, out1 = p1*is;
    float m2 = fmaxf(out0,out1);
    float lse = m2 + logf(__expf(out0-m2)+__expf(out1-m2));
    float ol = (label[s]!=0) ? out1 : out0;
    lt[s] = lse - ol;
    dout[1 + s*2]   = out0;
    dout[2 + s*2]   = out1;
  }
  __syncthreads();
  if (tid==0) {
    float sum=0.f;
    for (int s=0;s<S_;++s) sum += lt[s];
    dout[0] = sum * (1.0f/(float)S_);
  }
}

// ---------------------------------------------------------------- launch
extern "C" void kernel_launch(void* const* d_in, const int* in_sizes, int n_in,
                              void* d_out, int out_size, void* d_ws, size_t ws_size,
                              hipStream_t stream) {
  const float* pg_Wih  = (const float*)d_in[0];
  const float* pg_Whh  = (const float*)d_in[1];
  const float* pg_bih  = (const float*)d_in[2];
  const float* pg_bhh  = (const float*)d_in[3];
  const float* pa_W    = (const float*)d_in[4];
  const float* pa_b    = (const float*)d_in[5];
  const float* tl_Wall = (const float*)d_in[6];
  const float* tl_bWall= (const float*)d_in[7];
  const float* tl_Uall = (const float*)d_in[8];
  const float* tl_bUall= (const float*)d_in[9];
  const float* tl_Wd   = (const float*)d_in[10];
  const float* tl_bd   = (const float*)d_in[11];
  const float* ta_W    = (const float*)d_in[12];
  const float* ta_b    = (const float*)d_in[13];
  const float* sg_Wih  = (const float*)d_in[14];
  const float* sg_Whh  = (const float*)d_in[15];
  const float* sg_bih  = (const float*)d_in[16];
  const float* sg_bhh  = (const float*)d_in[17];
  const float* sa_W    = (const float*)d_in[18];
  const float* sa_b    = (const float*)d_in[19];
  const float* bi_W    = (const float*)d_in[20];
  const float* bi_b    = (const float*)d_in[21];
  const float* bl_W    = (const float*)d_in[22];
  const float* bl_b    = (const float*)d_in[23];
  const float* mha_Wq  = (const float*)d_in[24];
  const float* mha_bq  = (const float*)d_in[25];
  const float* mha_Wk  = (const float*)d_in[26];
  const float* mha_bk  = (const float*)d_in[27];
  const float* fc_W    = (const float*)d_in[28];
  const float* fc_b    = (const float*)d_in[29];
  const float* text    = (const float*)d_in[30];
  const float* price   = (const float*)d_in[31];
  const float* tstamps = (const float*)d_in[32];
  const int*   label   = (const int*)d_in[33];
  (void)in_sizes; (void)n_in; (void)out_size; (void)ws_size;

  // workspace layout
  short* WallBf = (short*)d_ws;                               // 13,107,200 sh
  short* Ubf    = WallBf + (size_t)S_*G4*FT_;                 // 1,638,400 sh
  short* Wdbf   = Ubf + (size_t)S_*G4*H_;                     // 409,600 sh
  unsigned short* GXbf = (unsigned short*)(Wdbf + (size_t)S_*H_*H_);  // 30,720,000 us
  float* taWT   = (float*)(GXbf + (size_t)S_*T_*D_*G4);       // 409,600 f
  float* outsb  = taWT + (size_t)S_*H_*H_;                    // 7,680,000 f
  float* news   = outsb + (size_t)S_*T_*D_*H_;                // 192,000 f
  float* xvec   = news + (size_t)S_*D_*H_;                    // 6,400 f
  float* feat   = xvec + (size_t)S_*H_;                       // 6,400 f
  float* Qg     = feat + (size_t)S_*H_;                       // 6,400 f
  float* Kg     = Qg   + (size_t)S_*H_;                       // 6,400 f
  float* scw    = Kg   + (size_t)S_*H_;                       // 40,000 f
  float* dout   = (float*)d_out;

  k_conv<<<2048, 256, 0, stream>>>(tl_Wall, tl_Uall, tl_Wd, ta_W, WallBf, Ubf, Wdbf, taWT);
  k_gemm<<<19*S_, 256, 0, stream>>>(text, WallBf, tl_bWall, tl_bUall, GXbf);
  k_recur<<<S_, 256, 0, stream>>>(GXbf, Ubf, Wdbf, tl_bd, tstamps, outsb);
  k_dayattn<<<S_*D_, 64, 0, stream>>>(outsb, taWT, ta_b, news);
  k_price_gru<<<S_, 256, 0, stream>>>(price, pg_Wih, pg_Whh, pg_bih, pg_bhh, pa_W, pa_b, xvec);
  k_stock<<<S_, 256, 0, stream>>>(news, sg_Wih, sg_Whh, sg_bih, sg_bhh, sa_W, sa_b, bi_W, bi_b, xvec, feat);
  k_head<<<1, 1024, 0, stream>>>(feat, bl_W, bl_b, mha_Wq, mha_bq, mha_Wk, mha_bk, fc_W, fc_b, label, Qg, Kg, scw, dout);
}

// Round 5
// 452.748 us; speedup vs baseline: 1.9185x; 1.2332x over previous
//
#include <hip/hip_runtime.h>
#include <math.h>

#define S_  100
#define D_  30
#define T_  40
#define FT_ 512
#define FP_ 3
#define H_  64
#define G3  192
#define G4  256
#define M_  (D_*T_)   // 1200

typedef __attribute__((ext_vector_type(8))) short short8_t;
typedef __attribute__((ext_vector_type(4))) short short4_t;
typedef __attribute__((ext_vector_type(4))) float f32x4;

__device__ __forceinline__ float sigm(float x){ return 1.0f/(1.0f+__expf(-x)); }
__device__ __forceinline__ float tanhfast(float x){
  float e = __expf(2.0f*x);
  return 1.0f - 2.0f/(e + 1.0f);
}
__device__ __forceinline__ short f2bf(float f){
  unsigned u = __builtin_bit_cast(unsigned, f);
  u += 0x7FFFu + ((u>>16)&1u);
  return (short)(u>>16);
}
__device__ __forceinline__ float bf2f(unsigned short u){
  unsigned x = ((unsigned)u) << 16;
  return __builtin_bit_cast(float, x);
}

// ---------------------------------------------------------------- K0: convert params
__global__ __launch_bounds__(256) void k_conv(
    const float* __restrict__ Wall, const float* __restrict__ Uall,
    const float* __restrict__ Wd, const float* __restrict__ taW,
    short* __restrict__ WallBf, short* __restrict__ Ubf,
    short* __restrict__ Wdbf, float* __restrict__ taWT)
{
  const int tid = blockIdx.x*256 + threadIdx.x;
  const int stride = gridDim.x*256;
  for (int i = tid; i < (S_*G4*FT_)/4; i += stride) {
    float4 v = reinterpret_cast<const float4*>(Wall)[i];
    short4_t o; o[0]=f2bf(v.x); o[1]=f2bf(v.y); o[2]=f2bf(v.z); o[3]=f2bf(v.w);
    reinterpret_cast<short4_t*>(WallBf)[i] = o;
  }
  for (int i = tid; i < (S_*G4*H_)/4; i += stride) {
    float4 v = reinterpret_cast<const float4*>(Uall)[i];
    short4_t o; o[0]=f2bf(v.x); o[1]=f2bf(v.y); o[2]=f2bf(v.z); o[3]=f2bf(v.w);
    reinterpret_cast<short4_t*>(Ubf)[i] = o;
  }
  for (int i = tid; i < (S_*H_*H_)/4; i += stride) {
    float4 v = reinterpret_cast<const float4*>(Wd)[i];
    short4_t o; o[0]=f2bf(v.x); o[1]=f2bf(v.y); o[2]=f2bf(v.z); o[3]=f2bf(v.w);
    reinterpret_cast<short4_t*>(Wdbf)[i] = o;
  }
  for (int i = tid; i < S_*H_*H_; i += stride) {
    int s = i >> 12, j = (i >> 6) & 63, c = i & 63;
    taWT[i] = taW[(s << 12) + (c << 6) + j];
  }
}

// ---------------------------------------------------------------- K1: GX[s][t][d][gate] (bf16)
#define LDT 72
__global__ __launch_bounds__(256) void k_gemm(
    const float* __restrict__ text, const short* __restrict__ WallBf,
    const float* __restrict__ bW, const float* __restrict__ bU,
    unsigned short* __restrict__ GX)
{
  const int bid = blockIdx.x;
  const int s  = bid / 19;
  const int mb = bid % 19;
  const int m0 = mb * 64;
  const int tid = threadIdx.x;
  const int lane = tid & 63, wave = tid >> 6;
  const int fr = lane & 15, fk = (lane >> 4) * 8;

  __shared__ short As[64][LDT];
  __shared__ short Bs[256][LDT];

  const float* X  = text + (size_t)s * ((size_t)M_*FT_);
  const short* Wb = WallBf + (size_t)s * ((size_t)G4*FT_);

  f32x4 acc[4][4];
  #pragma unroll
  for (int i=0;i<4;++i)
    #pragma unroll
    for (int j=0;j<4;++j) acc[i][j] = (f32x4)(0.f);

  for (int kp = 0; kp < 8; ++kp) {
    const int k0 = kp * 64;
    #pragma unroll
    for (int j = 0; j < 4; ++j) {
      int idx = tid + 256*j;
      int r = idx >> 4;
      int c4 = (idx & 15) * 4;
      int m = m0 + r;
      short4_t o;
      if (m < M_) {
        float4 v = *reinterpret_cast<const float4*>(X + (size_t)m*FT_ + k0 + c4);
        o[0]=f2bf(v.x); o[1]=f2bf(v.y); o[2]=f2bf(v.z); o[3]=f2bf(v.w);
      } else {
        o = (short4_t)(short)0;
      }
      *reinterpret_cast<short4_t*>(&As[r][c4]) = o;
    }
    #pragma unroll
    for (int j = 0; j < 8; ++j) {
      int idx = tid + 256*j;
      int row = idx >> 3, q = idx & 7;
      *reinterpret_cast<int4*>(&Bs[row][q*8]) =
          *reinterpret_cast<const int4*>(Wb + (size_t)row*FT_ + k0 + q*8);
    }
    __syncthreads();
    #pragma unroll
    for (int kw = 0; kw < 2; ++kw) {
      short8_t a[4], b[4];
      #pragma unroll
      for (int mt=0; mt<4; ++mt)
        a[mt] = *reinterpret_cast<const short8_t*>(&As[mt*16 + fr][kw*32 + fk]);
      #pragma unroll
      for (int nt=0; nt<4; ++nt)
        b[nt] = *reinterpret_cast<const short8_t*>(&Bs[wave*64 + nt*16 + fr][kw*32 + fk]);
      #pragma unroll
      for (int mt=0; mt<4; ++mt)
        #pragma unroll
        for (int nt=0; nt<4; ++nt)
          acc[mt][nt] = __builtin_amdgcn_mfma_f32_16x16x32_bf16(a[mt], b[nt], acc[mt][nt], 0,0,0);
    }
    __syncthreads();
  }

  const int l15 = lane & 15, h4 = (lane >> 4) * 4;
  #pragma unroll
  for (int nt = 0; nt < 4; ++nt) {
    const int n = wave*64 + nt*16 + l15;
    const float bias = bW[s*G4 + n] + bU[s*G4 + n];
    #pragma unroll
    for (int mt = 0; mt < 4; ++mt) {
      #pragma unroll
      for (int r = 0; r < 4; ++r) {
        const int m = m0 + mt*16 + h4 + r;
        if (m < M_) {
          const int d = m / T_, t = m % T_;
          GX[(((size_t)s*T_ + t)*D_ + d)*G4 + n] = (unsigned short)f2bf(acc[mt][nt][r] + bias);
        }
      }
    }
  }
}

// ---------------------------------------------------------------- K2: batched TimeLSTM, 2 blocks/stock x 15 days
#define RECUR_STEP(T_CUR, GXU, GXP)                                           \
  {                                                                           \
    f32x4 acc1_0=(f32x4)(0.f), acc1_1=(f32x4)(0.f);                           \
    f32x4 acc1_2=(f32x4)(0.f), acc1_3=(f32x4)(0.f);                           \
    f32x4 acc2=(f32x4)(0.f);                                                  \
    _Pragma("unroll")                                                         \
    for (int kw = 0; kw < 2; ++kw) {                                          \
      short8_t bfrag = *reinterpret_cast<const short8_t*>(&Hn[fr][kw*32+fk]); \
      acc1_0 = __builtin_amdgcn_mfma_f32_16x16x32_bf16(ureg[0][kw], bfrag, acc1_0,0,0,0); \
      acc1_1 = __builtin_amdgcn_mfma_f32_16x16x32_bf16(ureg[1][kw], bfrag, acc1_1,0,0,0); \
      acc1_2 = __builtin_amdgcn_mfma_f32_16x16x32_bf16(ureg[2][kw], bfrag, acc1_2,0,0,0); \
      acc1_3 = __builtin_amdgcn_mfma_f32_16x16x32_bf16(ureg[3][kw], bfrag, acc1_3,0,0,0); \
      short8_t cfrag = *reinterpret_cast<const short8_t*>(&Cn[fr][kw*32+fk]); \
      acc2 = __builtin_amdgcn_mfma_f32_16x16x32_bf16(wdreg[kw], cfrag, acc2,0,0,0); \
    }                                                                         \
    {                                                                         \
      const int tpf = ((T_CUR)+1 < T_) ? (T_CUR)+1 : (T_CUR);                 \
      const unsigned short* GXt = GX + ((size_t)(s*T_ + tpf)*D_ + d0)*G4;     \
      _Pragma("unroll")                                                       \
      for (int it = 0; it < 4; ++it) {                                        \
        int d = it*4 + wave;                                                  \
        if (d < 15) {                                                         \
          const unsigned short* p = GXt + d*G4 + lane;                        \
          GXP[it][0]=bf2f(p[0]);   GXP[it][1]=bf2f(p[64]);                    \
          GXP[it][2]=bf2f(p[128]); GXP[it][3]=bf2f(p[192]);                   \
        }                                                                     \
      }                                                                       \
    }                                                                         \
    *reinterpret_cast<f32x4*>(&G1[l15][wave*64 +  0 + h4]) = acc1_0;          \
    *reinterpret_cast<f32x4*>(&G1[l15][wave*64 + 16 + h4]) = acc1_1;          \
    *reinterpret_cast<f32x4*>(&G1[l15][wave*64 + 32 + h4]) = acc1_2;          \
    *reinterpret_cast<f32x4*>(&G1[l15][wave*64 + 48 + h4]) = acc1_3;          \
    *reinterpret_cast<f32x4*>(&G2l[l15][wave*16 + h4]) = acc2;                \
    __syncthreads();                                                          \
    {                                                                         \
      float* outp = outs + ((size_t)(s*T_ + (T_CUR))*D_ + d0)*H_;             \
      _Pragma("unroll")                                                       \
      for (int it = 0; it < 4; ++it) {                                        \
        int d = it*4 + wave;                                                  \
        if (d < 15) {                                                         \
          float gf = G1[d][lane]       + GXU[it][0];                          \
          float gi = G1[d][64 + lane]  + GXU[it][1];                          \
          float go = G1[d][128 + lane] + GXU[it][2];                          \
          float gc = G1[d][192 + lane] + GXU[it][3];                          \
          float f  = sigm(gf), ig = sigm(gi), og = sigm(go), ct = sigm(gc);   \
          float cs1 = tanhfast(G2l[d][lane] + bdl[lane]);                     \
          float tvv = tsl[d][(T_CUR)];                                        \
          float c  = Cf[d][lane];                                             \
          float cadj = c - cs1 + cs1*tvv;                                     \
          float c2 = f*cadj + ig*ct;                                          \
          float h2 = og*tanhfast(c2);                                         \
          Cf[d][lane] = c2; Cn[d][lane] = f2bf(c2); Hn[d][lane] = f2bf(h2);   \
          outp[d*H_ + lane] = h2;                                             \
        }                                                                     \
      }                                                                       \
    }                                                                         \
    __syncthreads();                                                          \
  }

__global__ __launch_bounds__(256) void k_recur(
    const unsigned short* __restrict__ GX, const short* __restrict__ Ubf,
    const short* __restrict__ Wdbf, const float* __restrict__ bd,
    const float* __restrict__ ts, float* __restrict__ outs)
{
  const int bid = blockIdx.x;
  const int s  = bid >> 1;
  const int d0 = (bid & 1) * 15;
  const int tid = threadIdx.x;
  const int lane = tid & 63, wave = tid >> 6;
  const int fr = lane & 15, fk = (lane >> 4) * 8;
  const int l15 = lane & 15, h4 = (lane >> 4) * 4;

  __shared__ float G1[16][260];
  __shared__ float G2l[16][68];
  __shared__ float Cf[16][68];
  __shared__ short Hn[16][72];
  __shared__ short Cn[16][72];
  __shared__ float tsl[16][T_];
  __shared__ float bdl[H_];

  for (int e = tid; e < 16*72; e += 256) { (&Hn[0][0])[e] = 0; (&Cn[0][0])[e] = 0; }
  for (int e = tid; e < 16*68; e += 256) (&Cf[0][0])[e] = 0.f;
  for (int e = tid; e < 15*T_; e += 256)
    tsl[e / T_][e % T_] = ts[((size_t)s*D_ + d0)*T_ + e];
  if (tid < H_) bdl[tid] = bd[s*H_ + tid];

  // hoist U, Wd fragments into registers (wave owns gate rows [wave*64, wave*64+64))
  short8_t ureg[4][2];
  short8_t wdreg[2];
  {
    const short* Ub  = Ubf  + (size_t)s*G4*H_;
    const short* Wdb = Wdbf + (size_t)s*H_*H_;
    #pragma unroll
    for (int mt = 0; mt < 4; ++mt)
      #pragma unroll
      for (int kw = 0; kw < 2; ++kw)
        ureg[mt][kw] = *reinterpret_cast<const short8_t*>(
            Ub + (size_t)(wave*64 + mt*16 + fr)*H_ + kw*32 + fk);
    #pragma unroll
    for (int kw = 0; kw < 2; ++kw)
      wdreg[kw] = *reinterpret_cast<const short8_t*>(
          Wdb + (size_t)(wave*16 + fr)*H_ + kw*32 + fk);
  }
  __syncthreads();

  float gxA[4][4], gxB[4][4];
  // prologue: prefetch t=0 into gxA
  {
    const unsigned short* GXt = GX + ((size_t)(s*T_ + 0)*D_ + d0)*G4;
    #pragma unroll
    for (int it = 0; it < 4; ++it) {
      int d = it*4 + wave;
      if (d < 15) {
        const unsigned short* p = GXt + d*G4 + lane;
        gxA[it][0]=bf2f(p[0]);   gxA[it][1]=bf2f(p[64]);
        gxA[it][2]=bf2f(p[128]); gxA[it][3]=bf2f(p[192]);
      }
    }
  }

  for (int t = 0; t < T_; t += 2) {
    RECUR_STEP(t,   gxA, gxB)
    RECUR_STEP(t+1, gxB, gxA)
  }
}

// ---------------------------------------------------------------- K3: day attention -> news
__global__ __launch_bounds__(64) void k_dayattn(
    const float* __restrict__ outs, const float* __restrict__ taWT,
    const float* __restrict__ tab, float* __restrict__ news)
{
  const int blk = blockIdx.x;
  const int s = blk / D_, d = blk % D_;
  const int lane = threadIdx.x;
  __shared__ float ol[T_][68];
  __shared__ float vv[H_];
  __shared__ float aw[64];

  #pragma unroll 4
  for (int t = 0; t < T_; ++t)
    ol[t][lane] = outs[((size_t)(s*T_ + t)*D_ + d)*H_ + lane];
  __syncthreads();

  float acc = tab[s*H_ + lane];
  const float* Wp = taWT + (size_t)s*H_*H_;
  #pragma unroll 8
  for (int j = 0; j < H_; ++j)
    acc = fmaf(Wp[j*H_ + lane], ol[T_-1][j], acc);
  vv[lane] = acc;
  __syncthreads();

  float sc = -1e30f;
  if (lane < T_) {
    sc = 0.f;
    for (int h = 0; h < H_; ++h) sc = fmaf(ol[lane][h], vv[h], sc);
  }
  float m = sc;
  #pragma unroll
  for (int off = 32; off > 0; off >>= 1) m = fmaxf(m, __shfl_xor(m, off, 64));
  float e = (lane < T_) ? __expf(sc - m) : 0.f;
  float sum = e;
  #pragma unroll
  for (int off = 32; off > 0; off >>= 1) sum += __shfl_xor(sum, off, 64);
  aw[lane] = e / sum;
  __syncthreads();

  float o = 0.f;
  #pragma unroll 8
  for (int t = 0; t < T_; ++t) o = fmaf(aw[t], ol[t][lane], o);
  news[((size_t)s*D_ + d)*H_ + lane] = o;
}

// ---------------------------------------------------------------- K4: price GRU + attention -> xvec
__global__ __launch_bounds__(256) void k_price_gru(
    const float* __restrict__ price, const float* __restrict__ Wih,
    const float* __restrict__ Whh, const float* __restrict__ bih,
    const float* __restrict__ bhh, const float* __restrict__ paW,
    const float* __restrict__ pab, float* __restrict__ xvec)
{
  const int s = blockIdx.x;
  const int tid = threadIdx.x;
  const int row = tid & 63, q = tid >> 6;
  __shared__ float hs[H_];
  __shared__ float outsb[D_][H_+1];
  __shared__ float gsum[128], gxn[64], ghn[64];
  __shared__ float pt[4][H_], vs[H_], as_[D_];

  float wih[3]; float whh[64]; float bihr=0.f, bhhr=0.f;
  if (tid < G3) {
    const float* wp = Wih + ((size_t)s*G3 + tid)*FP_;
    wih[0]=wp[0]; wih[1]=wp[1]; wih[2]=wp[2];
    const float* hp = Whh + ((size_t)s*G3 + tid)*H_;
    #pragma unroll
    for (int j=0;j<64;++j) whh[j]=hp[j];
    bihr = bih[s*G3+tid]; bhhr = bhh[s*G3+tid];
  }
  if (tid < H_) hs[tid]=0.f;
  __syncthreads();

  for (int d=0; d<D_; ++d) {
    const float* pp = price + ((size_t)s*D_ + d)*FP_;
    float p0=pp[0], p1=pp[1], p2=pp[2];
    if (tid < G3) {
      float gx = bihr + wih[0]*p0 + wih[1]*p1 + wih[2]*p2;
      float gh = bhhr;
      const float4* h4p = reinterpret_cast<const float4*>(hs);
      #pragma unroll
      for (int j4=0;j4<16;++j4) {
        float4 hv=h4p[j4];
        gh = fmaf(whh[j4*4+0],hv.x,gh);
        gh = fmaf(whh[j4*4+1],hv.y,gh);
        gh = fmaf(whh[j4*4+2],hv.z,gh);
        gh = fmaf(whh[j4*4+3],hv.w,gh);
      }
      if (tid < 128) gsum[tid] = gx + gh;
      else { gxn[tid-128] = gx; ghn[tid-128] = gh; }
    }
    __syncthreads();
    if (tid < H_) {
      float r = sigm(gsum[tid]);
      float z = sigm(gsum[64+tid]);
      float n = tanhf(gxn[tid] + r*ghn[tid]);
      float h2 = (1.f-z)*n + z*hs[tid];
      hs[tid]=h2; outsb[d][tid]=h2;
    }
    __syncthreads();
  }

  {
    const float* Wp = paW + ((size_t)s*H_ + row)*H_ + q*16;
    float p = 0.f;
    #pragma unroll
    for (int j=0;j<16;++j) p = fmaf(Wp[j], hs[q*16+j], p);
    pt[q][row] = p;
    __syncthreads();
    if (tid < H_) vs[tid] = pt[0][tid]+pt[1][tid]+pt[2][tid]+pt[3][tid] + pab[s*H_+tid];
    __syncthreads();
    if (tid < D_) {
      float sc = 0.f;
      for (int h=0;h<H_;++h) sc = fmaf(outsb[tid][h], vs[h], sc);
      as_[tid] = sc;
    }
    __syncthreads();
    if (tid == 0) {
      float m = -1e30f;
      for (int t=0;t<D_;++t) m = fmaxf(m, as_[t]);
      float sum = 0.f;
      for (int t=0;t<D_;++t) { float e = __expf(as_[t]-m); as_[t]=e; sum += e; }
      float inv = 1.0f/sum;
      for (int t=0;t<D_;++t) as_[t] *= inv;
    }
    __syncthreads();
    if (tid < H_) {
      float acc = 0.f;
      for (int t=0;t<D_;++t) acc = fmaf(as_[t], outsb[t][tid], acc);
      xvec[s*H_+tid] = acc;
    }
  }
}

// ---------------------------------------------------------------- K5: stock GRU over news + attention -> tvec
__global__ __launch_bounds__(256) void k_stock(
    const float* __restrict__ news, const float* __restrict__ Wih,
    const float* __restrict__ Whh, const float* __restrict__ bih,
    const float* __restrict__ bhh, const float* __restrict__ saW,
    const float* __restrict__ sab, float* __restrict__ tvecg)
{
  const int s = blockIdx.x;
  const int tid = threadIdx.x;
  const int row = tid & 63, q = tid >> 6;
  __shared__ float xs[H_], hs[H_];
  __shared__ float outsb[D_][H_+1];
  __shared__ float gsum[128], gxn[64], ghn[64];
  __shared__ float pt[4][H_], vs[H_], as_[D_];

  float wih[64]; float whh[64]; float bihr=0.f, bhhr=0.f;
  if (tid < G3) {
    const float* wp = Wih + ((size_t)s*G3 + tid)*H_;
    const float* hp = Whh + ((size_t)s*G3 + tid)*H_;
    #pragma unroll
    for (int j=0;j<64;++j) { wih[j]=wp[j]; whh[j]=hp[j]; }
    bihr = bih[s*G3+tid]; bhhr = bhh[s*G3+tid];
  }
  if (tid < H_) hs[tid]=0.f;
  __syncthreads();

  for (int d=0; d<D_; ++d) {
    if (tid < H_) xs[tid] = news[((size_t)s*D_ + d)*H_ + tid];
    __syncthreads();
    if (tid < G3) {
      float gx = bihr, gh = bhhr;
      const float4* x4 = reinterpret_cast<const float4*>(xs);
      const float4* h4p = reinterpret_cast<const float4*>(hs);
      #pragma unroll
      for (int j4=0;j4<16;++j4) {
        float4 xv=x4[j4]; float4 hv=h4p[j4];
        gx = fmaf(wih[j4*4+0],xv.x,gx); gx = fmaf(wih[j4*4+1],xv.y,gx);
        gx = fmaf(wih[j4*4+2],xv.z,gx); gx = fmaf(wih[j4*4+3],xv.w,gx);
        gh = fmaf(whh[j4*4+0],hv.x,gh); gh = fmaf(whh[j4*4+1],hv.y,gh);
        gh = fmaf(whh[j4*4+2],hv.z,gh); gh = fmaf(whh[j4*4+3],hv.w,gh);
      }
      if (tid < 128) gsum[tid] = gx + gh;
      else { gxn[tid-128] = gx; ghn[tid-128] = gh; }
    }
    __syncthreads();
    if (tid < H_) {
      float r = sigm(gsum[tid]);
      float z = sigm(gsum[64+tid]);
      float n = tanhf(gxn[tid] + r*ghn[tid]);
      float h2 = (1.f-z)*n + z*hs[tid];
      hs[tid]=h2; outsb[d][tid]=h2;
    }
    __syncthreads();
  }

  {
    const float* Wp = saW + ((size_t)s*H_ + row)*H_ + q*16;
    float p = 0.f;
    #pragma unroll
    for (int j=0;j<16;++j) p = fmaf(Wp[j], hs[q*16+j], p);
    pt[q][row] = p;
    __syncthreads();
    if (tid < H_) vs[tid] = pt[0][tid]+pt[1][tid]+pt[2][tid]+pt[3][tid] + sab[s*H_+tid];
    __syncthreads();
    if (tid < D_) {
      float sc = 0.f;
      for (int h=0;h<H_;++h) sc = fmaf(outsb[tid][h], vs[h], sc);
      as_[tid] = sc;
    }
    __syncthreads();
    if (tid == 0) {
      float m = -1e30f;
      for (int t=0;t<D_;++t) m = fmaxf(m, as_[t]);
      float sum = 0.f;
      for (int t=0;t<D_;++t) { float e = __expf(as_[t]-m); as_[t]=e; sum += e; }
      float inv = 1.0f/sum;
      for (int t=0;t<D_;++t) as_[t] *= inv;
    }
    __syncthreads();
    if (tid < H_) {
      float acc = 0.f;
      for (int t=0;t<D_;++t) acc = fmaf(as_[t], outsb[t][tid], acc);
      tvecg[s*H_+tid] = acc;
    }
  }
}

// ---------------------------------------------------------------- K5b: bilinear -> feat (400 blocks, BW-bound)
__global__ __launch_bounds__(256) void k_bilin(
    const float* __restrict__ tvec, const float* __restrict__ xvec,
    const float* __restrict__ biW, const float* __restrict__ bib,
    float* __restrict__ feat)
{
  const int s = blockIdx.x >> 2;
  const int k0 = (blockIdx.x & 3) * 16;
  const int tid = threadIdx.x;
  const int lane = tid & 63, w = tid >> 6;
  __shared__ float pmat[H_*H_];
  __shared__ float tl[H_], xl[H_];
  if (tid < H_) { tl[tid] = tvec[s*H_+tid]; xl[tid] = xvec[s*H_+tid]; }
  __syncthreads();
  for (int e = tid; e < H_*H_; e += 256) pmat[e] = tl[e>>6]*xl[e&63];
  __syncthreads();
  const float4* P4 = reinterpret_cast<const float4*>(pmat);
  #pragma unroll
  for (int kk = 0; kk < 4; ++kk) {
    int k = k0 + kk*4 + w;
    const float4* W4 = reinterpret_cast<const float4*>(biW + ((size_t)s*H_ + k)*H_*H_);
    float acc = 0.f;
    #pragma unroll
    for (int r = 0; r < 16; ++r) {
      float4 wv = W4[r*64 + lane];
      float4 pv = P4[r*64 + lane];
      acc += wv.x*pv.x + wv.y*pv.y + wv.z*pv.z + wv.w*pv.w;
    }
    #pragma unroll
    for (int off = 32; off > 0; off >>= 1) acc += __shfl_down(acc, off, 64);
    if (lane == 0) feat[s*H_ + k] = tanhf(acc + bib[s*H_+k]);
  }
}

// ---------------------------------------------------------------- K6: head
__global__ __launch_bounds__(1024) void k_head(
    const float* __restrict__ feat, const float* __restrict__ blW,
    const float* __restrict__ blb, const float* __restrict__ Wq,
    const float* __restrict__ bq, const float* __restrict__ Wk,
    const float* __restrict__ bk, const float* __restrict__ fcW,
    const float* __restrict__ fcb, const int* __restrict__ label,
    float* __restrict__ Qg, float* __restrict__ Kg, float* __restrict__ scw,
    float* __restrict__ dout)
{
  const int tid = threadIdx.x;
  __shared__ float fs[S_*H_];
  __shared__ float mhs[S_*H_];
  __shared__ float o1[S_*2];
  __shared__ float lt[S_];

  for (int e=tid; e<S_*H_; e+=1024) fs[e] = feat[e];
  __syncthreads();

  if (tid < 2*S_) {
    int s = tid>>1, c = tid&1;
    const float* w = blW + ((size_t)(S_-1)*2 + c)*H_;
    float a = blb[(S_-1)*2 + c];
    for (int h=0;h<H_;++h) a = fmaf(fs[s*H_+h], w[h], a);
    o1[tid] = tanhf(a);
  }
  for (int e=tid; e<S_*H_; e+=1024) {
    int s = e>>6, o = e&63;
    float aq = bq[o], ak = bk[o];
    const float* wq = Wq + o*H_;
    const float* wk = Wk + o*H_;
    for (int h=0;h<H_;++h) { float f = fs[s*H_+h]; aq = fmaf(f, wq[h], aq); ak = fmaf(f, wk[h], ak); }
    Qg[e]=aq; Kg[e]=ak;
  }
  __syncthreads();

  if (tid < 4*S_) {
    int s = tid % S_, hd = tid / S_;
    const float* qr = Qg + s*H_ + hd*16;
    float m = -1e30f;
    for (int t=0;t<S_;++t) {
      const float* kr = Kg + t*H_ + hd*16;
      float sc=0.f;
      #pragma unroll
      for (int d2=0; d2<16; ++d2) sc = fmaf(qr[d2], kr[d2], sc);
      sc *= 0.25f;
      scw[(size_t)tid*S_+t]=sc;
      m = fmaxf(m, sc);
    }
    float sum=0.f;
    for (int t=0;t<S_;++t) { float e=__expf(scw[(size_t)tid*S_+t]-m); scw[(size_t)tid*S_+t]=e; sum+=e; }
    float inv=1.f/sum;
    float acc[16];
    #pragma unroll
    for (int d2=0;d2<16;++d2) acc[d2]=0.f;
    for (int t=0;t<S_;++t) {
      float a = scw[(size_t)tid*S_+t]*inv;
      #pragma unroll
      for (int d2=0;d2<16;++d2) acc[d2] = fmaf(a, fs[t*H_ + hd*16 + d2], acc[d2]);
    }
    #pragma unroll
    for (int d2=0;d2<16;++d2) mhs[s*H_ + hd*16 + d2] = acc[d2];
  }
  __syncthreads();

  if (tid < S_) {
    int s = tid;
    float e0 = fcb[0], e1 = fcb[1];
    for (int h=0;h<H_;++h) { float mv = mhs[s*H_+h]; e0 = fmaf(mv, fcW[h], e0); e1 = fmaf(mv, fcW[H_+h], e1); }
    float x0 = e0>0.f?e0:(__expf(e0)-1.f);
    float x1 = e1>0.f?e1:(__expf(e1)-1.f);
    float y0 = x0 + o1[s*2], y1 = x1 + o1[s*2+1];
    float mm = fmaxf(y0,y1);
    float p0 = __expf(y0-mm), p1=__expf(y1-mm);
    float is = 1.f/(p0+p1);
    float out0 = p0*is, out1 = p1*is;
    float m2 = fmaxf(out0,out1);
    float lse = m2 + logf(__expf(out0-m2)+__expf(out1-m2));
    float ol = (label[s]!=0) ? out1 : out0;
    lt[s] = lse - ol;
    dout[1 + s*2]   = out0;
    dout[2 + s*2]   = out1;
  }
  __syncthreads();
  if (tid==0) {
    float sum=0.f;
    for (int s=0;s<S_;++s) sum += lt[s];
    dout[0] = sum * (1.0f/(float)S_);
  }
}

// ---------------------------------------------------------------- launch
extern "C" void kernel_launch(void* const* d_in, const int* in_sizes, int n_in,
                              void* d_out, int out_size, void* d_ws, size_t ws_size,
                              hipStream_t stream) {
  const float* pg_Wih  = (const float*)d_in[0];
  const float* pg_Whh  = (const float*)d_in[1];
  const float* pg_bih  = (const float*)d_in[2];
  const float* pg_bhh  = (const float*)d_in[3];
  const float* pa_W    = (const float*)d_in[4];
  const float* pa_b    = (const float*)d_in[5];
  const float* tl_Wall = (const float*)d_in[6];
  const float* tl_bWall= (const float*)d_in[7];
  const float* tl_Uall = (const float*)d_in[8];
  const float* tl_bUall= (const float*)d_in[9];
  const float* tl_Wd   = (const float*)d_in[10];
  const float* tl_bd   = (const float*)d_in[11];
  const float* ta_W    = (const float*)d_in[12];
  const float* ta_b    = (const float*)d_in[13];
  const float* sg_Wih  = (const float*)d_in[14];
  const float* sg_Whh  = (const float*)d_in[15];
  const float* sg_bih  = (const float*)d_in[16];
  const float* sg_bhh  = (const float*)d_in[17];
  const float* sa_W    = (const float*)d_in[18];
  const float* sa_b    = (const float*)d_in[19];
  const float* bi_W    = (const float*)d_in[20];
  const float* bi_b    = (const float*)d_in[21];
  const float* bl_W    = (const float*)d_in[22];
  const float* bl_b    = (const float*)d_in[23];
  const float* mha_Wq  = (const float*)d_in[24];
  const float* mha_bq  = (const float*)d_in[25];
  const float* mha_Wk  = (const float*)d_in[26];
  const float* mha_bk  = (const float*)d_in[27];
  const float* fc_W    = (const float*)d_in[28];
  const float* fc_b    = (const float*)d_in[29];
  const float* text    = (const float*)d_in[30];
  const float* price   = (const float*)d_in[31];
  const float* tstamps = (const float*)d_in[32];
  const int*   label   = (const int*)d_in[33];
  (void)in_sizes; (void)n_in; (void)out_size; (void)ws_size;

  // workspace layout
  short* WallBf = (short*)d_ws;                               // 13,107,200 sh
  short* Ubf    = WallBf + (size_t)S_*G4*FT_;                 // 1,638,400 sh
  short* Wdbf   = Ubf + (size_t)S_*G4*H_;                     // 409,600 sh
  unsigned short* GXbf = (unsigned short*)(Wdbf + (size_t)S_*H_*H_);  // 30,720,000 us
  float* taWT   = (float*)(GXbf + (size_t)S_*T_*D_*G4);       // 409,600 f
  float* outsb  = taWT + (size_t)S_*H_*H_;                    // 7,680,000 f
  float* news   = outsb + (size_t)S_*T_*D_*H_;                // 192,000 f
  float* xvec   = news + (size_t)S_*D_*H_;                    // 6,400 f
  float* feat   = xvec + (size_t)S_*H_;                       // 6,400 f
  float* Qg     = feat + (size_t)S_*H_;                       // 6,400 f
  float* Kg     = Qg   + (size_t)S_*H_;                       // 6,400 f
  float* scw    = Kg   + (size_t)S_*H_;                       // 40,000 f
  float* tvecg  = scw  + (size_t)4*S_*S_;                     // 6,400 f
  float* dout   = (float*)d_out;

  k_conv<<<2048, 256, 0, stream>>>(tl_Wall, tl_Uall, tl_Wd, ta_W, WallBf, Ubf, Wdbf, taWT);
  k_gemm<<<19*S_, 256, 0, stream>>>(text, WallBf, tl_bWall, tl_bUall, GXbf);
  k_recur<<<2*S_, 256, 0, stream>>>(GXbf, Ubf, Wdbf, tl_bd, tstamps, outsb);
  k_dayattn<<<S_*D_, 64, 0, stream>>>(outsb, taWT, ta_b, news);
  k_price_gru<<<S_, 256, 0, stream>>>(price, pg_Wih, pg_Whh, pg_bih, pg_bhh, pa_W, pa_b, xvec);
  k_stock<<<S_, 256, 0, stream>>>(news, sg_Wih, sg_Whh, sg_bih, sg_bhh, sa_W, sa_b, tvecg);
  k_bilin<<<4*S_, 256, 0, stream>>>(tvecg, xvec, bi_W, bi_b, feat);
  k_head<<<1, 1024, 0, stream>>>(feat, bl_W, bl_b, mha_Wq, mha_bq, mha_Wk, mha_bk, fc_W, fc_b, label, Qg, Kg, scw, dout);
}